// Round 1
// baseline (468.587 us; speedup 1.0000x reference)
//
#include <hip/hip_runtime.h>

#define S_TOK 8192
#define M_DIM 512
#define E_NUM 8
#define CAP   1024
#define H_DIM 1024

// ---------------------------------------------------------------------------
// K1: gating. One wave (64 lanes) per token. logits = x @ wg, softmax, argmax.
// Writes idx[s], gate_top[s] (top gate prob, pre-capacity), gates_full[s][8].
// ---------------------------------------------------------------------------
__global__ __launch_bounds__(256) void gate_kernel(
    const float* __restrict__ feats, const float* __restrict__ wg,
    int* __restrict__ idx, float* __restrict__ gate_top,
    float* __restrict__ gates_full)
{
    const int wave = threadIdx.x >> 6;
    const int lane = threadIdx.x & 63;
    const int s = blockIdx.x * 4 + wave;   // grid = 2048 blocks -> s in [0,8192)

    const float* xrow = feats + (size_t)s * M_DIM;
    float p[8];
#pragma unroll
    for (int e = 0; e < 8; ++e) p[e] = 0.f;

    for (int i = 0; i < M_DIM / 64; ++i) {
        const int m = lane + 64 * i;
        const float x = xrow[m];
        const float* wrow = wg + m * 8;
#pragma unroll
        for (int e = 0; e < 8; ++e) p[e] += x * wrow[e];
    }
    // 64-lane butterfly reduction for each of 8 experts
#pragma unroll
    for (int e = 0; e < 8; ++e) {
        float v = p[e];
#pragma unroll
        for (int off = 1; off < 64; off <<= 1) v += __shfl_xor(v, off, 64);
        p[e] = v;
    }
    if (lane == 0) {
        float mx = p[0];
#pragma unroll
        for (int e = 1; e < 8; ++e) mx = fmaxf(mx, p[e]);
        float ex[8], sum = 0.f;
#pragma unroll
        for (int e = 0; e < 8; ++e) { ex[e] = expf(p[e] - mx); sum += ex[e]; }
        const float inv = 1.0f / sum;
        // argmax on logits (== argmax of softmax), first-occurrence on ties
        int best = 0; float bl = p[0];
#pragma unroll
        for (int e = 1; e < 8; ++e) { if (p[e] > bl) { bl = p[e]; best = e; } }
#pragma unroll
        for (int e = 0; e < 8; ++e) gates_full[s * 8 + e] = ex[e] * inv;
        idx[s] = best;
        gate_top[s] = ex[best] * inv;
    }
}

// ---------------------------------------------------------------------------
// K2: single-workgroup blocked scan. Exact order-of-arrival cumsum per expert,
// capacity drop, per-expert token lists, l_aux. 256 threads x 32 tokens each.
// ---------------------------------------------------------------------------
__global__ __launch_bounds__(256) void scan_kernel(
    const int* __restrict__ idx, const float* __restrict__ gate_top,
    const float* __restrict__ gates_full,
    float* __restrict__ gate_final, int* __restrict__ token_list,
    int* __restrict__ kept, float* __restrict__ laux)
{
    __shared__ int   cnts[256][8];
    __shared__ float msum[256][8];
    __shared__ int   totals[8];
    __shared__ float mesum[8];

    const int t = threadIdx.x;
    const int base = t * 32;

    int   c[8];
    float g[8];
#pragma unroll
    for (int e = 0; e < 8; ++e) { c[e] = 0; g[e] = 0.f; }

    for (int i = 0; i < 32; ++i) {
        const int ei = idx[base + i];
#pragma unroll
        for (int e = 0; e < 8; ++e) c[e] += (ei == e) ? 1 : 0;
#pragma unroll
        for (int e = 0; e < 8; ++e) g[e] += gates_full[(base + i) * 8 + e];
    }
#pragma unroll
    for (int e = 0; e < 8; ++e) { cnts[t][e] = c[e]; msum[t][e] = g[e]; }
    __syncthreads();

    if (t < 8) {   // serial exclusive scan over the 256 chunks, expert t
        int run = 0; float ms = 0.f;
        for (int r = 0; r < 256; ++r) {
            const int v = cnts[r][t];
            cnts[r][t] = run;
            run += v;
            ms += msum[r][t];
        }
        totals[t] = run;
        mesum[t] = ms;
        kept[t] = run < CAP ? run : CAP;
    }
    __syncthreads();

    if (t == 0) {
        float l = 0.f;
        for (int e = 0; e < 8; ++e) {
            const int ke = totals[e] < CAP ? totals[e] : CAP;
            l += (mesum[e] / (float)S_TOK) * ((float)ke / (float)S_TOK);
        }
        laux[0] = l * (float)E_NUM;
    }

    // phase C: assign slots in arrival order
    int rc[8];
#pragma unroll
    for (int e = 0; e < 8; ++e) rc[e] = cnts[t][e];

    for (int i = 0; i < 32; ++i) {
        const int s = base + i;
        const int ei = idx[s];
        int loc = 0;
#pragma unroll
        for (int e = 0; e < 8; ++e) {
            if (ei == e) { loc = rc[e]; rc[e] = rc[e] + 1; }
        }
        const bool keepit = loc < CAP;
        gate_final[s] = keepit ? gate_top[s] : 0.f;
        if (keepit) token_list[ei * CAP + loc] = s;
    }
}

// ---------------------------------------------------------------------------
// K3: grouped GEMM1 + ReLU.  h[e,c,:] = relu(x_{tok(e,c)} @ w1[e] + b1[e])
// Block: 32 tokens x 128 h-cols. 256 thr = 8 row-groups x 32 col-groups,
// each thread 4 tokens x 4 cols. X staged in LDS per 128-m chunk (16 KB).
// ---------------------------------------------------------------------------
__global__ __launch_bounds__(256) void ffn1_kernel(
    const float* __restrict__ feats, const float* __restrict__ w1,
    const float* __restrict__ b1, const int* __restrict__ token_list,
    const int* __restrict__ kept, float* __restrict__ h)
{
    const int b = blockIdx.x;          // 8 * 32 * 8 = 2048 blocks
    const int e = b >> 8;
    const int rem = b & 255;
    const int ct = rem >> 3, jt = rem & 7;
    const int c0 = ct * 32, j0 = jt * 128;
    const int ke = kept[e];
    if (c0 >= ke) return;
    const int nvalid = (ke - c0) < 32 ? (ke - c0) : 32;

    __shared__ float XL[32][128];
    __shared__ int srow[32];
    const int t = threadIdx.x;
    if (t < 32) srow[t] = (t < nvalid) ? token_list[e * CAP + c0 + t] : -1;
    __syncthreads();

    const int tr = t >> 5, tc = t & 31;
    float4 acc[4];
#pragma unroll
    for (int i = 0; i < 4; ++i) acc[i] = make_float4(0.f, 0.f, 0.f, 0.f);

    for (int mc = 0; mc < 4; ++mc) {
        const int mb = mc * 128;
        // stage X[:,mb:mb+128] -> LDS (gathered rows)
#pragma unroll
        for (int k = 0; k < 4; ++k) {
            const int f = t + 256 * k;       // float4 index, 1024 total
            const int r = f >> 5, c4 = f & 31;
            const int s = srow[r];
            float4 v = make_float4(0.f, 0.f, 0.f, 0.f);
            if (s >= 0)
                v = ((const float4*)(feats + (size_t)s * M_DIM + mb))[c4];
            *((float4*)&XL[r][c4 * 4]) = v;
        }
        __syncthreads();

        const float* wbase = w1 + ((size_t)e * M_DIM + mb) * H_DIM + j0 + tc * 4;
#pragma unroll 4
        for (int m = 0; m < 128; ++m) {
            const float4 w4 = *((const float4*)(wbase + (size_t)m * H_DIM));
            const float x0 = XL[4 * tr + 0][m];
            const float x1 = XL[4 * tr + 1][m];
            const float x2 = XL[4 * tr + 2][m];
            const float x3 = XL[4 * tr + 3][m];
            acc[0].x += x0 * w4.x; acc[0].y += x0 * w4.y; acc[0].z += x0 * w4.z; acc[0].w += x0 * w4.w;
            acc[1].x += x1 * w4.x; acc[1].y += x1 * w4.y; acc[1].z += x1 * w4.z; acc[1].w += x1 * w4.w;
            acc[2].x += x2 * w4.x; acc[2].y += x2 * w4.y; acc[2].z += x2 * w4.z; acc[2].w += x2 * w4.w;
            acc[3].x += x3 * w4.x; acc[3].y += x3 * w4.y; acc[3].z += x3 * w4.z; acc[3].w += x3 * w4.w;
        }
        __syncthreads();
    }

    const float4 bv = *((const float4*)(b1 + e * H_DIM + j0 + tc * 4));
#pragma unroll
    for (int i = 0; i < 4; ++i) {
        const int r = 4 * tr + i;
        if (r < nvalid) {
            float4 o;
            o.x = fmaxf(acc[i].x + bv.x, 0.f);
            o.y = fmaxf(acc[i].y + bv.y, 0.f);
            o.z = fmaxf(acc[i].z + bv.z, 0.f);
            o.w = fmaxf(acc[i].w + bv.w, 0.f);
            *((float4*)(h + (size_t)(e * CAP + c0 + r) * H_DIM + j0 + tc * 4)) = o;
        }
    }
}

// ---------------------------------------------------------------------------
// K4: grouped GEMM2 + gate-scaled scatter. out[s,:] = g_s*(h[e,c]@w2[e]+b2[e])
// Block: 32 tokens x 128 out-cols; same register blocking as K3.
// ---------------------------------------------------------------------------
__global__ __launch_bounds__(256) void ffn2_kernel(
    const float* __restrict__ h, const float* __restrict__ w2,
    const float* __restrict__ b2, const int* __restrict__ token_list,
    const int* __restrict__ kept, const float* __restrict__ gate_final,
    float* __restrict__ out)
{
    const int b = blockIdx.x;          // 8 * 32 * 4 = 1024 blocks
    const int e = b >> 7;
    const int rem = b & 127;
    const int ct = rem >> 2, nt = rem & 3;
    const int c0 = ct * 32, n0 = nt * 128;
    const int ke = kept[e];
    if (c0 >= ke) return;
    const int nvalid = (ke - c0) < 32 ? (ke - c0) : 32;

    __shared__ float HL[32][128];
    const int t = threadIdx.x;
    const int tr = t >> 5, tc = t & 31;
    float4 acc[4];
#pragma unroll
    for (int i = 0; i < 4; ++i) acc[i] = make_float4(0.f, 0.f, 0.f, 0.f);

    for (int kc = 0; kc < 8; ++kc) {
        const int kb = kc * 128;
#pragma unroll
        for (int q = 0; q < 4; ++q) {
            const int f = t + 256 * q;
            const int r = f >> 5, c4 = f & 31;
            float4 v = make_float4(0.f, 0.f, 0.f, 0.f);
            if (r < nvalid)
                v = ((const float4*)(h + (size_t)(e * CAP + c0 + r) * H_DIM + kb))[c4];
            *((float4*)&HL[r][c4 * 4]) = v;
        }
        __syncthreads();

        const float* wbase = w2 + ((size_t)e * H_DIM + kb) * M_DIM + n0 + tc * 4;
#pragma unroll 4
        for (int k = 0; k < 128; ++k) {
            const float4 w4 = *((const float4*)(wbase + (size_t)k * M_DIM));
            const float x0 = HL[4 * tr + 0][k];
            const float x1 = HL[4 * tr + 1][k];
            const float x2 = HL[4 * tr + 2][k];
            const float x3 = HL[4 * tr + 3][k];
            acc[0].x += x0 * w4.x; acc[0].y += x0 * w4.y; acc[0].z += x0 * w4.z; acc[0].w += x0 * w4.w;
            acc[1].x += x1 * w4.x; acc[1].y += x1 * w4.y; acc[1].z += x1 * w4.z; acc[1].w += x1 * w4.w;
            acc[2].x += x2 * w4.x; acc[2].y += x2 * w4.y; acc[2].z += x2 * w4.z; acc[2].w += x2 * w4.w;
            acc[3].x += x3 * w4.x; acc[3].y += x3 * w4.y; acc[3].z += x3 * w4.z; acc[3].w += x3 * w4.w;
        }
        __syncthreads();
    }

    const float4 bv = *((const float4*)(b2 + e * M_DIM + n0 + tc * 4));
#pragma unroll
    for (int i = 0; i < 4; ++i) {
        const int r = 4 * tr + i;
        if (r < nvalid) {
            const int s = token_list[e * CAP + c0 + r];
            const float gsc = gate_final[s];
            float4 o;
            o.x = gsc * (acc[i].x + bv.x);
            o.y = gsc * (acc[i].y + bv.y);
            o.z = gsc * (acc[i].z + bv.z);
            o.w = gsc * (acc[i].w + bv.w);
            *((float4*)(out + (size_t)s * M_DIM + n0 + tc * 4)) = o;
        }
    }
}

// ---------------------------------------------------------------------------
extern "C" void kernel_launch(void* const* d_in, const int* in_sizes, int n_in,
                              void* d_out, int out_size, void* d_ws, size_t ws_size,
                              hipStream_t stream) {
    const float* feats = (const float*)d_in[0];   // [8192, 512]
    const float* wg    = (const float*)d_in[1];   // [512, 8]
    const float* w1    = (const float*)d_in[2];   // [8, 512, 1024]
    const float* b1    = (const float*)d_in[3];   // [8, 1024]
    const float* w2    = (const float*)d_in[4];   // [8, 1024, 512]
    const float* b2    = (const float*)d_in[5];   // [8, 512]
    float* out = (float*)d_out;                   // [8192*512] ++ [1] l_aux

    char* ws = (char*)d_ws;
    float* h = (float*)ws;                                   // 32 MB
    size_t off = (size_t)S_TOK * H_DIM * 4;
    int*   idx        = (int*)(ws + off);   off += (size_t)S_TOK * 4;
    float* gate_top   = (float*)(ws + off); off += (size_t)S_TOK * 4;
    float* gate_final = (float*)(ws + off); off += (size_t)S_TOK * 4;
    float* gates_full = (float*)(ws + off); off += (size_t)S_TOK * 8 * 4;
    int*   token_list = (int*)(ws + off);   off += (size_t)S_TOK * 4;
    int*   kept       = (int*)(ws + off);   off += 64;
    (void)ws_size; (void)n_in; (void)in_sizes;

    // zero output (dropped-token rows must be 0); l_aux overwritten by scan
    hipMemsetAsync(d_out, 0, (size_t)out_size * sizeof(float), stream);

    gate_kernel<<<S_TOK / 4, 256, 0, stream>>>(feats, wg, idx, gate_top, gates_full);
    scan_kernel<<<1, 256, 0, stream>>>(idx, gate_top, gates_full, gate_final,
                                       token_list, kept, out + (size_t)S_TOK * M_DIM);
    ffn1_kernel<<<E_NUM * 32 * 8, 256, 0, stream>>>(feats, w1, b1, token_list, kept, h);
    ffn2_kernel<<<E_NUM * 32 * 4, 256, 0, stream>>>(h, w2, b2, token_list, kept,
                                                    gate_final, out);
}

// Round 2
// 214.049 us; speedup vs baseline: 2.1892x; 2.1892x over previous
//
#include <hip/hip_runtime.h>

#define S_TOK 8192
#define M_DIM 512
#define E_NUM 8
#define CAP   1024
#define H_DIM 1024

typedef __attribute__((ext_vector_type(8))) short bf16x8;
typedef __attribute__((ext_vector_type(4))) float f32x4;

__device__ static inline unsigned short f2bf(float f) {
    unsigned int u = __float_as_uint(f);
    unsigned int r = (u + 0x7fffu + ((u >> 16) & 1u)) >> 16;
    return (unsigned short)r;
}

__device__ static inline void async_copy16(const void* g, void* l) {
    __builtin_amdgcn_global_load_lds(
        (const __attribute__((address_space(1))) void*)g,
        (__attribute__((address_space(3))) void*)l, 16, 0, 0);
}

// ---------------------------------------------------------------------------
// K1: gating. One wave per token. logits = x @ wg, softmax, argmax. (fp32)
// ---------------------------------------------------------------------------
__global__ __launch_bounds__(256) void gate_kernel(
    const float* __restrict__ feats, const float* __restrict__ wg,
    int* __restrict__ idx, float* __restrict__ gate_top,
    float* __restrict__ gates_full)
{
    const int wave = threadIdx.x >> 6;
    const int lane = threadIdx.x & 63;
    const int s = blockIdx.x * 4 + wave;

    const float* xrow = feats + (size_t)s * M_DIM;
    float p[8];
#pragma unroll
    for (int e = 0; e < 8; ++e) p[e] = 0.f;

    for (int i = 0; i < M_DIM / 64; ++i) {
        const int m = lane + 64 * i;
        const float x = xrow[m];
        const float* wrow = wg + m * 8;
#pragma unroll
        for (int e = 0; e < 8; ++e) p[e] += x * wrow[e];
    }
#pragma unroll
    for (int e = 0; e < 8; ++e) {
        float v = p[e];
#pragma unroll
        for (int off = 1; off < 64; off <<= 1) v += __shfl_xor(v, off, 64);
        p[e] = v;
    }
    if (lane == 0) {
        float mx = p[0];
#pragma unroll
        for (int e = 1; e < 8; ++e) mx = fmaxf(mx, p[e]);
        float ex[8], sum = 0.f;
#pragma unroll
        for (int e = 0; e < 8; ++e) { ex[e] = expf(p[e] - mx); sum += ex[e]; }
        const float inv = 1.0f / sum;
        int best = 0; float bl = p[0];
#pragma unroll
        for (int e = 1; e < 8; ++e) { if (p[e] > bl) { bl = p[e]; best = e; } }
#pragma unroll
        for (int e = 0; e < 8; ++e) gates_full[s * 8 + e] = ex[e] * inv;
        idx[s] = best;
        gate_top[s] = ex[best] * inv;
    }
}

// ---------------------------------------------------------------------------
// K2: single-workgroup scan: exact arrival-order cumsum, capacity, lists, l_aux.
// Also prefills token_list with S_TOK (-> zero row) for unfilled slots.
// ---------------------------------------------------------------------------
__global__ __launch_bounds__(256) void scan_kernel(
    const int* __restrict__ idx, const float* __restrict__ gate_top,
    const float* __restrict__ gates_full,
    float* __restrict__ gate_final, int* __restrict__ token_list,
    int* __restrict__ kept, float* __restrict__ laux)
{
    __shared__ int   cnts[256][8];
    __shared__ float msum[256][8];
    __shared__ int   totals[8];
    __shared__ float mesum[8];

    const int t = threadIdx.x;
    const int base = t * 32;

    // prefill token_list with the zero-row sentinel
    for (int i = t; i < E_NUM * CAP; i += 256) token_list[i] = S_TOK;

    int   c[8];
    float g[8];
#pragma unroll
    for (int e = 0; e < 8; ++e) { c[e] = 0; g[e] = 0.f; }

    for (int i = 0; i < 32; ++i) {
        const int ei = idx[base + i];
#pragma unroll
        for (int e = 0; e < 8; ++e) c[e] += (ei == e) ? 1 : 0;
#pragma unroll
        for (int e = 0; e < 8; ++e) g[e] += gates_full[(base + i) * 8 + e];
    }
#pragma unroll
    for (int e = 0; e < 8; ++e) { cnts[t][e] = c[e]; msum[t][e] = g[e]; }
    __syncthreads();

    if (t < 8) {
        int run = 0; float ms = 0.f;
        for (int r = 0; r < 256; ++r) {
            const int v = cnts[r][t];
            cnts[r][t] = run;
            run += v;
            ms += msum[r][t];
        }
        totals[t] = run;
        mesum[t] = ms;
        kept[t] = run < CAP ? run : CAP;
    }
    __syncthreads();

    if (t == 0) {
        float l = 0.f;
        for (int e = 0; e < 8; ++e) {
            const int ke = totals[e] < CAP ? totals[e] : CAP;
            l += (mesum[e] / (float)S_TOK) * ((float)ke / (float)S_TOK);
        }
        laux[0] = l * (float)E_NUM;
    }

    int rc[8];
#pragma unroll
    for (int e = 0; e < 8; ++e) rc[e] = cnts[t][e];

    for (int i = 0; i < 32; ++i) {
        const int s = base + i;
        const int ei = idx[s];
        int loc = 0;
#pragma unroll
        for (int e = 0; e < 8; ++e) {
            if (ei == e) { loc = rc[e]; rc[e] = rc[e] + 1; }
        }
        const bool keepit = loc < CAP;
        gate_final[s] = keepit ? gate_top[s] : 0.f;
        if (keepit) token_list[ei * CAP + loc] = s;
    }
}

// ---------------------------------------------------------------------------
// Conversions: fp32 -> bf16. feats gets an extra zero row at index S_TOK.
// w1/w2 are stored transposed per expert: [e][n][k] so B-frags are contiguous.
// ---------------------------------------------------------------------------
__global__ __launch_bounds__(256) void convert_x(
    const float* __restrict__ x, unsigned short* __restrict__ xb)
{
    const size_t i4 = ((size_t)blockIdx.x * 256 + threadIdx.x) * 4;
    const size_t n_in = (size_t)S_TOK * M_DIM;
    const size_t n_tot = (size_t)(S_TOK + 1) * M_DIM;
    if (i4 >= n_tot) return;
    ushort4 o;
    if (i4 < n_in) {
        const float4 v = *(const float4*)(x + i4);
        o.x = f2bf(v.x); o.y = f2bf(v.y); o.z = f2bf(v.z); o.w = f2bf(v.w);
    } else {
        o.x = o.y = o.z = o.w = 0;
    }
    *(ushort4*)(xb + i4) = o;
}

__global__ __launch_bounds__(256) void convert_w1(
    const float* __restrict__ w1, unsigned short* __restrict__ w1t)
{
    // w1: [8][512][1024] -> w1t: [8][1024][512]
    __shared__ float tile[32][33];
    const int b = blockIdx.x;                 // 8 * 16 * 32
    const int e = b >> 9;
    const int kt = (b >> 5) & 15;
    const int nt = b & 31;
    const int k0 = kt * 32, n0 = nt * 32;
    const int t = threadIdx.x;
    const int r = t >> 5, c = t & 31;
#pragma unroll
    for (int i = 0; i < 4; ++i) {
        const int row = r + i * 8;
        tile[row][c] = w1[((size_t)e * 512 + k0 + row) * 1024 + n0 + c];
    }
    __syncthreads();
#pragma unroll
    for (int i = 0; i < 4; ++i) {
        const int row = r + i * 8;
        w1t[((size_t)e * 1024 + n0 + row) * 512 + k0 + c] = f2bf(tile[c][row]);
    }
}

__global__ __launch_bounds__(256) void convert_w2(
    const float* __restrict__ w2, unsigned short* __restrict__ w2t)
{
    // w2: [8][1024][512] -> w2t: [8][512][1024]
    __shared__ float tile[32][33];
    const int b = blockIdx.x;                 // 8 * 32 * 16
    const int e = b >> 9;
    const int kt = (b >> 4) & 31;
    const int nt = b & 15;
    const int k0 = kt * 32, n0 = nt * 32;
    const int t = threadIdx.x;
    const int r = t >> 5, c = t & 31;
#pragma unroll
    for (int i = 0; i < 4; ++i) {
        const int row = r + i * 8;
        tile[row][c] = w2[((size_t)e * 1024 + k0 + row) * 512 + n0 + c];
    }
    __syncthreads();
#pragma unroll
    for (int i = 0; i < 4; ++i) {
        const int row = r + i * 8;
        w2t[((size_t)e * 512 + n0 + row) * 1024 + k0 + c] = f2bf(tile[c][row]);
    }
}

// ---------------------------------------------------------------------------
// K3: MFMA grouped GEMM1 + bias + ReLU -> h (bf16).
// 128x128 tile, 4 waves (2x2), 16x16x32 bf16 MFMA, 4x4 frags/wave, BK=64.
// A rows gathered via token_list (invalid slots -> zero row S_TOK).
// ---------------------------------------------------------------------------
__global__ __launch_bounds__(256) void ffn1_mfma(
    const unsigned short* __restrict__ xb, const unsigned short* __restrict__ w1t,
    const float* __restrict__ b1, const int* __restrict__ tok,
    const int* __restrict__ kept, unsigned short* __restrict__ h)
{
    const int b = blockIdx.x;          // 8 e * 8 ct * 8 nt = 512
    const int e = b >> 6;
    const int ct = (b >> 3) & 7;
    const int nt = b & 7;
    const int c0 = ct * 128, n0 = nt * 128;
    if (c0 >= kept[e]) return;

    __shared__ __align__(16) short Alds[128 * 64];
    __shared__ __align__(16) short Blds[128 * 64];
    __shared__ int srow[128];

    const int t = threadIdx.x;
    const int wave = t >> 6, lane = t & 63;
    const int wm = wave & 1, wn = wave >> 1;
    const int q = lane >> 4, lr = lane & 15;

    if (t < 128) srow[t] = tok[e * CAP + c0 + t];

    f32x4 acc[4][4];
#pragma unroll
    for (int mi = 0; mi < 4; ++mi)
#pragma unroll
        for (int ni = 0; ni < 4; ++ni) acc[mi][ni] = (f32x4){0.f, 0.f, 0.f, 0.f};

    for (int kb = 0; kb < M_DIM; kb += 64) {
        __syncthreads();
#pragma unroll
        for (int i = 0; i < 4; ++i) {
            const int lin = (i * 4 + wave) * 64 + lane;   // 16B chunk id, 0..1023
            const int row = lin >> 3, ch = lin & 7;
            async_copy16(xb + (size_t)srow[row] * M_DIM + kb + ch * 8, Alds + lin * 8);
        }
#pragma unroll
        for (int i = 0; i < 4; ++i) {
            const int lin = (i * 4 + wave) * 64 + lane;
            const int row = lin >> 3, ch = lin & 7;
            async_copy16(w1t + ((size_t)e * H_DIM + n0 + row) * M_DIM + kb + ch * 8,
                         Blds + lin * 8);
        }
        __syncthreads();

#pragma unroll
        for (int kk = 0; kk < 64; kk += 32) {
            bf16x8 af[4], bfv[4];
#pragma unroll
            for (int mi = 0; mi < 4; ++mi)
                af[mi] = *(const bf16x8*)(Alds + (wm * 64 + mi * 16 + lr) * 64 + kk + q * 8);
#pragma unroll
            for (int ni = 0; ni < 4; ++ni)
                bfv[ni] = *(const bf16x8*)(Blds + (wn * 64 + ni * 16 + lr) * 64 + kk + q * 8);
#pragma unroll
            for (int mi = 0; mi < 4; ++mi)
#pragma unroll
                for (int ni = 0; ni < 4; ++ni)
                    acc[mi][ni] = __builtin_amdgcn_mfma_f32_16x16x32_bf16(
                        af[mi], bfv[ni], acc[mi][ni], 0, 0, 0);
        }
    }

#pragma unroll
    for (int ni = 0; ni < 4; ++ni) {
        const int col = n0 + wn * 64 + ni * 16 + lr;
        const float bias = b1[e * H_DIM + col];
#pragma unroll
        for (int mi = 0; mi < 4; ++mi) {
            const int rowl = wm * 64 + mi * 16 + q * 4;
            const size_t basep = (size_t)(e * CAP + c0 + rowl) * H_DIM + col;
#pragma unroll
            for (int r = 0; r < 4; ++r) {
                const float v = fmaxf(acc[mi][ni][r] + bias, 0.f);
                h[basep + (size_t)r * H_DIM] = f2bf(v);
            }
        }
    }
}

// ---------------------------------------------------------------------------
// K4: MFMA grouped GEMM2 + bias + gate-scaled scatter to out rows.
// ---------------------------------------------------------------------------
__global__ __launch_bounds__(256) void ffn2_mfma(
    const unsigned short* __restrict__ h, const unsigned short* __restrict__ w2t,
    const float* __restrict__ b2, const int* __restrict__ tok,
    const int* __restrict__ kept, const float* __restrict__ gate_final,
    float* __restrict__ out)
{
    const int b = blockIdx.x;          // 8 e * 8 ct * 4 nt = 256
    const int e = b >> 5;
    const int ct = (b >> 2) & 7;
    const int nt = b & 3;
    const int c0 = ct * 128, n0 = nt * 128;
    if (c0 >= kept[e]) return;

    __shared__ __align__(16) short Alds[128 * 64];
    __shared__ __align__(16) short Blds[128 * 64];

    const int t = threadIdx.x;
    const int wave = t >> 6, lane = t & 63;
    const int wm = wave & 1, wn = wave >> 1;
    const int q = lane >> 4, lr = lane & 15;

    f32x4 acc[4][4];
#pragma unroll
    for (int mi = 0; mi < 4; ++mi)
#pragma unroll
        for (int ni = 0; ni < 4; ++ni) acc[mi][ni] = (f32x4){0.f, 0.f, 0.f, 0.f};

    for (int kb = 0; kb < H_DIM; kb += 64) {
        __syncthreads();
#pragma unroll
        for (int i = 0; i < 4; ++i) {
            const int lin = (i * 4 + wave) * 64 + lane;
            const int row = lin >> 3, ch = lin & 7;
            async_copy16(h + (size_t)(e * CAP + c0 + row) * H_DIM + kb + ch * 8,
                         Alds + lin * 8);
        }
#pragma unroll
        for (int i = 0; i < 4; ++i) {
            const int lin = (i * 4 + wave) * 64 + lane;
            const int row = lin >> 3, ch = lin & 7;
            async_copy16(w2t + ((size_t)e * M_DIM + n0 + row) * H_DIM + kb + ch * 8,
                         Blds + lin * 8);
        }
        __syncthreads();

#pragma unroll
        for (int kk = 0; kk < 64; kk += 32) {
            bf16x8 af[4], bfv[4];
#pragma unroll
            for (int mi = 0; mi < 4; ++mi)
                af[mi] = *(const bf16x8*)(Alds + (wm * 64 + mi * 16 + lr) * 64 + kk + q * 8);
#pragma unroll
            for (int ni = 0; ni < 4; ++ni)
                bfv[ni] = *(const bf16x8*)(Blds + (wn * 64 + ni * 16 + lr) * 64 + kk + q * 8);
#pragma unroll
            for (int mi = 0; mi < 4; ++mi)
#pragma unroll
                for (int ni = 0; ni < 4; ++ni)
                    acc[mi][ni] = __builtin_amdgcn_mfma_f32_16x16x32_bf16(
                        af[mi], bfv[ni], acc[mi][ni], 0, 0, 0);
        }
    }

#pragma unroll
    for (int ni = 0; ni < 4; ++ni) {
        const int col = n0 + wn * 64 + ni * 16 + lr;
        const float bias = b2[e * M_DIM + col];
#pragma unroll
        for (int mi = 0; mi < 4; ++mi) {
            const int rowl = wm * 64 + mi * 16 + q * 4;
#pragma unroll
            for (int r = 0; r < 4; ++r) {
                const int slot = c0 + rowl + r;
                const int tokid = tok[e * CAP + slot];
                if (tokid != S_TOK) {
                    const float gsc = gate_final[tokid];
                    out[(size_t)tokid * M_DIM + col] = gsc * (acc[mi][ni][r] + bias);
                }
            }
        }
    }
}

// ---------------------------------------------------------------------------
extern "C" void kernel_launch(void* const* d_in, const int* in_sizes, int n_in,
                              void* d_out, int out_size, void* d_ws, size_t ws_size,
                              hipStream_t stream) {
    const float* feats = (const float*)d_in[0];   // [8192, 512]
    const float* wg    = (const float*)d_in[1];   // [512, 8]
    const float* w1    = (const float*)d_in[2];   // [8, 512, 1024]
    const float* b1    = (const float*)d_in[3];   // [8, 1024]
    const float* w2    = (const float*)d_in[4];   // [8, 1024, 512]
    const float* b2    = (const float*)d_in[5];   // [8, 512]
    float* out = (float*)d_out;                   // [8192*512] ++ [1] l_aux

    char* ws = (char*)d_ws;
    size_t off = 0;
    unsigned short* h   = (unsigned short*)(ws + off); off += (size_t)E_NUM * CAP * H_DIM * 2;
    unsigned short* xb  = (unsigned short*)(ws + off); off += (size_t)(S_TOK + 1) * M_DIM * 2;
    unsigned short* w1t = (unsigned short*)(ws + off); off += (size_t)E_NUM * H_DIM * M_DIM * 2;
    unsigned short* w2t = (unsigned short*)(ws + off); off += (size_t)E_NUM * M_DIM * H_DIM * 2;
    int*   idx        = (int*)(ws + off);   off += (size_t)S_TOK * 4;
    float* gate_top   = (float*)(ws + off); off += (size_t)S_TOK * 4;
    float* gate_final = (float*)(ws + off); off += (size_t)S_TOK * 4;
    float* gates_full = (float*)(ws + off); off += (size_t)S_TOK * 8 * 4;
    int*   token_list = (int*)(ws + off);   off += (size_t)S_TOK * 4;
    int*   kept       = (int*)(ws + off);   off += 64;
    (void)ws_size; (void)n_in; (void)in_sizes;

    hipMemsetAsync(d_out, 0, (size_t)out_size * sizeof(float), stream);

    convert_x<<<(int)(((size_t)(S_TOK + 1) * M_DIM / 4 + 255) / 256), 256, 0, stream>>>(feats, xb);
    convert_w1<<<8 * 16 * 32, 256, 0, stream>>>(w1, w1t);
    convert_w2<<<8 * 32 * 16, 256, 0, stream>>>(w2, w2t);

    gate_kernel<<<S_TOK / 4, 256, 0, stream>>>(feats, wg, idx, gate_top, gates_full);
    scan_kernel<<<1, 256, 0, stream>>>(idx, gate_top, gates_full, gate_final,
                                       token_list, kept, out + (size_t)S_TOK * M_DIM);

    ffn1_mfma<<<E_NUM * 8 * 8, 256, 0, stream>>>(xb, w1t, b1, token_list, kept, h);
    ffn2_mfma<<<E_NUM * 8 * 4, 256, 0, stream>>>(h, w2t, b2, token_list, kept,
                                                 gate_final, out);
}

// Round 3
// 193.794 us; speedup vs baseline: 2.4180x; 1.1045x over previous
//
#include <hip/hip_runtime.h>

#define S_TOK 8192
#define M_DIM 512
#define E_NUM 8
#define CAP   1024
#define H_DIM 1024

typedef __attribute__((ext_vector_type(8))) short bf16x8;
typedef __attribute__((ext_vector_type(4))) float f32x4;

__device__ static inline unsigned short f2bf(float f) {
    unsigned int u = __float_as_uint(f);
    unsigned int r = (u + 0x7fffu + ((u >> 16) & 1u)) >> 16;
    return (unsigned short)r;
}

__device__ static inline void async_copy16(const void* g, void* l) {
    __builtin_amdgcn_global_load_lds(
        (const __attribute__((address_space(1))) void*)g,
        (__attribute__((address_space(3))) void*)l, 16, 0, 0);
}

// ---------------------------------------------------------------------------
// K1: gating + x->bf16 conversion. One wave per token.
// ---------------------------------------------------------------------------
__global__ __launch_bounds__(256) void gate_kernel(
    const float* __restrict__ feats, const float* __restrict__ wg,
    int* __restrict__ idx, float* __restrict__ gate_top,
    float* __restrict__ gates_full, unsigned short* __restrict__ xb)
{
    const int wave = threadIdx.x >> 6;
    const int lane = threadIdx.x & 63;
    const int s = blockIdx.x * 4 + wave;

    const float* xrow = feats + (size_t)s * M_DIM;

    // bf16 conversion: lane covers 8 consecutive elements -> one 16B store
    {
        const int m0 = lane * 8;
        const float4 va = *(const float4*)(xrow + m0);
        const float4 vb = *(const float4*)(xrow + m0 + 4);
        bf16x8 o;
        o[0] = (short)f2bf(va.x); o[1] = (short)f2bf(va.y);
        o[2] = (short)f2bf(va.z); o[3] = (short)f2bf(va.w);
        o[4] = (short)f2bf(vb.x); o[5] = (short)f2bf(vb.y);
        o[6] = (short)f2bf(vb.z); o[7] = (short)f2bf(vb.w);
        *(bf16x8*)(xb + (size_t)s * M_DIM + m0) = o;
        if (blockIdx.x == 0 && wave == 0) {  // zero sentinel row
            bf16x8 z = (bf16x8){0,0,0,0,0,0,0,0};
            *(bf16x8*)(xb + (size_t)S_TOK * M_DIM + m0) = z;
        }
    }

    float p[8];
#pragma unroll
    for (int e = 0; e < 8; ++e) p[e] = 0.f;

    for (int i = 0; i < M_DIM / 64; ++i) {
        const int m = lane + 64 * i;
        const float x = xrow[m];
        const float* wrow = wg + m * 8;
#pragma unroll
        for (int e = 0; e < 8; ++e) p[e] += x * wrow[e];
    }
#pragma unroll
    for (int e = 0; e < 8; ++e) {
        float v = p[e];
#pragma unroll
        for (int off = 1; off < 64; off <<= 1) v += __shfl_xor(v, off, 64);
        p[e] = v;
    }
    if (lane == 0) {
        float mx = p[0];
#pragma unroll
        for (int e = 1; e < 8; ++e) mx = fmaxf(mx, p[e]);
        float ex[8], sum = 0.f;
#pragma unroll
        for (int e = 0; e < 8; ++e) { ex[e] = expf(p[e] - mx); sum += ex[e]; }
        const float inv = 1.0f / sum;
        int best = 0; float bl = p[0];
#pragma unroll
        for (int e = 1; e < 8; ++e) { if (p[e] > bl) { bl = p[e]; best = e; } }
#pragma unroll
        for (int e = 0; e < 8; ++e) gates_full[s * 8 + e] = ex[e] * inv;
        idx[s] = best;
        gate_top[s] = ex[best] * inv;
    }
}

// ---------------------------------------------------------------------------
// K2: single-workgroup scan + capacity + token lists + l_aux + dropped list.
// ---------------------------------------------------------------------------
__global__ __launch_bounds__(256) void scan_kernel(
    const int* __restrict__ idx, const float* __restrict__ gate_top,
    const float* __restrict__ gates_full,
    float* __restrict__ gate_final, int* __restrict__ token_list,
    int* __restrict__ kept, float* __restrict__ laux,
    int* __restrict__ dropped, int* __restrict__ ndrop)
{
    __shared__ int   cnts[256][8];
    __shared__ float msum[256][8];
    __shared__ int   totals[8];
    __shared__ float mesum[8];
    __shared__ int   dropctr;

    const int t = threadIdx.x;
    const int base = t * 32;

    for (int i = t; i < E_NUM * CAP; i += 256) token_list[i] = S_TOK;
    if (t == 0) dropctr = 0;

    int   c[8];
    float g[8];
#pragma unroll
    for (int e = 0; e < 8; ++e) { c[e] = 0; g[e] = 0.f; }

    for (int i = 0; i < 32; ++i) {
        const int ei = idx[base + i];
#pragma unroll
        for (int e = 0; e < 8; ++e) c[e] += (ei == e) ? 1 : 0;
#pragma unroll
        for (int e = 0; e < 8; ++e) g[e] += gates_full[(base + i) * 8 + e];
    }
#pragma unroll
    for (int e = 0; e < 8; ++e) { cnts[t][e] = c[e]; msum[t][e] = g[e]; }
    __syncthreads();

    if (t < 8) {
        int run = 0; float ms = 0.f;
        for (int r = 0; r < 256; ++r) {
            const int v = cnts[r][t];
            cnts[r][t] = run;
            run += v;
            ms += msum[r][t];
        }
        totals[t] = run;
        mesum[t] = ms;
        kept[t] = run < CAP ? run : CAP;
    }
    __syncthreads();

    if (t == 0) {
        float l = 0.f;
        for (int e = 0; e < 8; ++e) {
            const int ke = totals[e] < CAP ? totals[e] : CAP;
            l += (mesum[e] / (float)S_TOK) * ((float)ke / (float)S_TOK);
        }
        laux[0] = l * (float)E_NUM;
    }

    int rc[8];
#pragma unroll
    for (int e = 0; e < 8; ++e) rc[e] = cnts[t][e];

    for (int i = 0; i < 32; ++i) {
        const int s = base + i;
        const int ei = idx[s];
        int loc = 0;
#pragma unroll
        for (int e = 0; e < 8; ++e) {
            if (ei == e) { loc = rc[e]; rc[e] = rc[e] + 1; }
        }
        const bool keepit = loc < CAP;
        gate_final[s] = keepit ? gate_top[s] : 0.f;
        if (keepit) {
            token_list[ei * CAP + loc] = s;
        } else {
            const int d = atomicAdd(&dropctr, 1);
            dropped[d] = s;
        }
    }
    __syncthreads();
    if (t == 0) ndrop[0] = dropctr;
}

// ---------------------------------------------------------------------------
// zero_dropped: zero out rows of dropped tokens (replaces full memset).
// ---------------------------------------------------------------------------
__global__ __launch_bounds__(256) void zero_dropped(
    const int* __restrict__ dropped, const int* __restrict__ ndrop,
    float* __restrict__ out)
{
    const int n = ndrop[0];
    const int t = threadIdx.x;
    for (int d = blockIdx.x; d < n; d += gridDim.x) {
        const int s = dropped[d];
        float2 z = make_float2(0.f, 0.f);
        *(float2*)(out + (size_t)s * M_DIM + t * 2) = z;
    }
}

// ---------------------------------------------------------------------------
// Merged weight convert+transpose: w1 [8][512][1024]->w1t [8][1024][512],
//                                  w2 [8][1024][512]->w2t [8][512][1024]
// ---------------------------------------------------------------------------
__global__ __launch_bounds__(256) void convert_w(
    const float* __restrict__ w1, unsigned short* __restrict__ w1t,
    const float* __restrict__ w2, unsigned short* __restrict__ w2t)
{
    __shared__ float tile[32][33];
    int b = blockIdx.x;
    const float* src; unsigned short* dst;
    int e, k0, n0, K, N;
    if (b < 4096) {
        e = b >> 9; k0 = ((b >> 5) & 15) * 32; n0 = (b & 31) * 32;
        K = 512; N = 1024; src = w1; dst = w1t;
    } else {
        b -= 4096;
        e = b >> 9; k0 = ((b >> 4) & 31) * 32; n0 = (b & 15) * 32;
        K = 1024; N = 512; src = w2; dst = w2t;
    }
    const int t = threadIdx.x;
    const int r = t >> 5, c = t & 31;
#pragma unroll
    for (int i = 0; i < 4; ++i) {
        const int row = r + i * 8;
        tile[row][c] = src[((size_t)e * K + k0 + row) * N + n0 + c];
    }
    __syncthreads();
#pragma unroll
    for (int i = 0; i < 4; ++i) {
        const int row = r + i * 8;
        dst[((size_t)e * N + n0 + row) * K + k0 + c] = f2bf(tile[c][row]);
    }
}

// ---------------------------------------------------------------------------
// K3: MFMA grouped GEMM1 + bias + ReLU -> h (bf16). 128x128 tile, BK=64.
// Expert in LOW bits of blockIdx -> expert<->XCD affinity for weight L2 reuse.
// ---------------------------------------------------------------------------
__global__ __launch_bounds__(256) void ffn1_mfma(
    const unsigned short* __restrict__ xb, const unsigned short* __restrict__ w1t,
    const float* __restrict__ b1, const int* __restrict__ tok,
    const int* __restrict__ kept, unsigned short* __restrict__ h)
{
    const int b = blockIdx.x;          // 512 = 8ct*8nt*8e
    const int e = b & 7;
    const int r = b >> 3;
    const int ct = r >> 3, nt = r & 7;
    const int c0 = ct * 128, n0 = nt * 128;
    if (c0 >= kept[e]) return;

    __shared__ __align__(16) short Alds[128 * 64];
    __shared__ __align__(16) short Blds[128 * 64];
    __shared__ int srow[128];

    const int t = threadIdx.x;
    const int wave = t >> 6, lane = t & 63;
    const int wm = wave & 1, wn = wave >> 1;
    const int q = lane >> 4, lr = lane & 15;

    if (t < 128) srow[t] = tok[e * CAP + c0 + t];

    f32x4 acc[4][4];
#pragma unroll
    for (int mi = 0; mi < 4; ++mi)
#pragma unroll
        for (int ni = 0; ni < 4; ++ni) acc[mi][ni] = (f32x4){0.f, 0.f, 0.f, 0.f};

    for (int kb = 0; kb < M_DIM; kb += 64) {
        __syncthreads();
#pragma unroll
        for (int i = 0; i < 4; ++i) {
            const int lin = (i * 4 + wave) * 64 + lane;
            const int row = lin >> 3, ch = lin & 7;
            async_copy16(xb + (size_t)srow[row] * M_DIM + kb + ch * 8, Alds + lin * 8);
        }
#pragma unroll
        for (int i = 0; i < 4; ++i) {
            const int lin = (i * 4 + wave) * 64 + lane;
            const int row = lin >> 3, ch = lin & 7;
            async_copy16(w1t + ((size_t)e * H_DIM + n0 + row) * M_DIM + kb + ch * 8,
                         Blds + lin * 8);
        }
        __syncthreads();

#pragma unroll
        for (int kk = 0; kk < 64; kk += 32) {
            bf16x8 af[4], bfv[4];
#pragma unroll
            for (int mi = 0; mi < 4; ++mi)
                af[mi] = *(const bf16x8*)(Alds + (wm * 64 + mi * 16 + lr) * 64 + kk + q * 8);
#pragma unroll
            for (int ni = 0; ni < 4; ++ni)
                bfv[ni] = *(const bf16x8*)(Blds + (wn * 64 + ni * 16 + lr) * 64 + kk + q * 8);
#pragma unroll
            for (int mi = 0; mi < 4; ++mi)
#pragma unroll
                for (int ni = 0; ni < 4; ++ni)
                    acc[mi][ni] = __builtin_amdgcn_mfma_f32_16x16x32_bf16(
                        af[mi], bfv[ni], acc[mi][ni], 0, 0, 0);
        }
    }

#pragma unroll
    for (int ni = 0; ni < 4; ++ni) {
        const int col = n0 + wn * 64 + ni * 16 + lr;
        const float bias = b1[e * H_DIM + col];
#pragma unroll
        for (int mi = 0; mi < 4; ++mi) {
            const int rowl = wm * 64 + mi * 16 + q * 4;
            const size_t basep = (size_t)(e * CAP + c0 + rowl) * H_DIM + col;
#pragma unroll
            for (int r2 = 0; r2 < 4; ++r2) {
                const float v = fmaxf(acc[mi][ni][r2] + bias, 0.f);
                h[basep + (size_t)r2 * H_DIM] = f2bf(v);
            }
        }
    }
}

// ---------------------------------------------------------------------------
// K4: MFMA grouped GEMM2 + bias + gate-scaled scatter. 128x64 tile, BK=64.
// 512 blocks -> 2 blocks/CU. Expert in low bits for XCD affinity.
// ---------------------------------------------------------------------------
__global__ __launch_bounds__(256) void ffn2_mfma(
    const unsigned short* __restrict__ h, const unsigned short* __restrict__ w2t,
    const float* __restrict__ b2, const int* __restrict__ tok,
    const int* __restrict__ kept, const float* __restrict__ gate_final,
    float* __restrict__ out)
{
    const int b = blockIdx.x;          // 512 = 8ct*8nt*8e
    const int e = b & 7;
    const int r = b >> 3;
    const int ct = r >> 3, nt = r & 7;
    const int c0 = ct * 128, n0 = nt * 64;
    if (c0 >= kept[e]) return;

    __shared__ __align__(16) short Alds[128 * 64];
    __shared__ __align__(16) short Blds[64 * 64];

    const int t = threadIdx.x;
    const int wave = t >> 6, lane = t & 63;
    const int wm = wave & 1, wn = wave >> 1;
    const int q = lane >> 4, lr = lane & 15;

    f32x4 acc[4][2];
#pragma unroll
    for (int mi = 0; mi < 4; ++mi)
#pragma unroll
        for (int ni = 0; ni < 2; ++ni) acc[mi][ni] = (f32x4){0.f, 0.f, 0.f, 0.f};

    for (int kb = 0; kb < H_DIM; kb += 64) {
        __syncthreads();
#pragma unroll
        for (int i = 0; i < 4; ++i) {
            const int lin = (i * 4 + wave) * 64 + lane;
            const int row = lin >> 3, ch = lin & 7;
            async_copy16(h + (size_t)(e * CAP + c0 + row) * H_DIM + kb + ch * 8,
                         Alds + lin * 8);
        }
#pragma unroll
        for (int i = 0; i < 2; ++i) {
            const int lin = (i * 4 + wave) * 64 + lane;
            const int row = lin >> 3, ch = lin & 7;
            async_copy16(w2t + ((size_t)e * M_DIM + n0 + row) * H_DIM + kb + ch * 8,
                         Blds + lin * 8);
        }
        __syncthreads();

#pragma unroll
        for (int kk = 0; kk < 64; kk += 32) {
            bf16x8 af[4], bfv[2];
#pragma unroll
            for (int mi = 0; mi < 4; ++mi)
                af[mi] = *(const bf16x8*)(Alds + (wm * 64 + mi * 16 + lr) * 64 + kk + q * 8);
#pragma unroll
            for (int ni = 0; ni < 2; ++ni)
                bfv[ni] = *(const bf16x8*)(Blds + (wn * 32 + ni * 16 + lr) * 64 + kk + q * 8);
#pragma unroll
            for (int mi = 0; mi < 4; ++mi)
#pragma unroll
                for (int ni = 0; ni < 2; ++ni)
                    acc[mi][ni] = __builtin_amdgcn_mfma_f32_16x16x32_bf16(
                        af[mi], bfv[ni], acc[mi][ni], 0, 0, 0);
        }
    }

#pragma unroll
    for (int ni = 0; ni < 2; ++ni) {
        const int col = n0 + wn * 32 + ni * 16 + lr;
        const float bias = b2[e * M_DIM + col];
#pragma unroll
        for (int mi = 0; mi < 4; ++mi) {
            const int rowl = wm * 64 + mi * 16 + q * 4;
#pragma unroll
            for (int r2 = 0; r2 < 4; ++r2) {
                const int slot = c0 + rowl + r2;
                const int tokid = tok[e * CAP + slot];
                if (tokid != S_TOK) {
                    const float gsc = gate_final[tokid];
                    out[(size_t)tokid * M_DIM + col] = gsc * (acc[mi][ni][r2] + bias);
                }
            }
        }
    }
}

// ---------------------------------------------------------------------------
extern "C" void kernel_launch(void* const* d_in, const int* in_sizes, int n_in,
                              void* d_out, int out_size, void* d_ws, size_t ws_size,
                              hipStream_t stream) {
    const float* feats = (const float*)d_in[0];
    const float* wg    = (const float*)d_in[1];
    const float* w1    = (const float*)d_in[2];
    const float* b1    = (const float*)d_in[3];
    const float* w2    = (const float*)d_in[4];
    const float* b2    = (const float*)d_in[5];
    float* out = (float*)d_out;

    char* ws = (char*)d_ws;
    size_t off = 0;
    unsigned short* h   = (unsigned short*)(ws + off); off += (size_t)E_NUM * CAP * H_DIM * 2;
    unsigned short* xb  = (unsigned short*)(ws + off); off += (size_t)(S_TOK + 1) * M_DIM * 2;
    unsigned short* w1t = (unsigned short*)(ws + off); off += (size_t)E_NUM * H_DIM * M_DIM * 2;
    unsigned short* w2t = (unsigned short*)(ws + off); off += (size_t)E_NUM * M_DIM * H_DIM * 2;
    int*   idx        = (int*)(ws + off);   off += (size_t)S_TOK * 4;
    float* gate_top   = (float*)(ws + off); off += (size_t)S_TOK * 4;
    float* gate_final = (float*)(ws + off); off += (size_t)S_TOK * 4;
    float* gates_full = (float*)(ws + off); off += (size_t)S_TOK * 8 * 4;
    int*   token_list = (int*)(ws + off);   off += (size_t)S_TOK * 4;
    int*   dropped    = (int*)(ws + off);   off += (size_t)S_TOK * 4;
    int*   kept       = (int*)(ws + off);   off += 64;
    int*   ndrop      = (int*)(ws + off);   off += 64;
    (void)ws_size; (void)n_in; (void)in_sizes;

    gate_kernel<<<S_TOK / 4, 256, 0, stream>>>(feats, wg, idx, gate_top,
                                               gates_full, xb);
    convert_w<<<8192, 256, 0, stream>>>(w1, w1t, w2, w2t);
    scan_kernel<<<1, 256, 0, stream>>>(idx, gate_top, gates_full, gate_final,
                                       token_list, kept, out + (size_t)S_TOK * M_DIM,
                                       dropped, ndrop);
    zero_dropped<<<256, 256, 0, stream>>>(dropped, ndrop, out);
    ffn1_mfma<<<512, 256, 0, stream>>>(xb, w1t, b1, token_list, kept, h);
    ffn2_mfma<<<512, 256, 0, stream>>>(h, w2t, b2, token_list, kept,
                                       gate_final, out);
}

// Round 4
// 186.094 us; speedup vs baseline: 2.5180x; 1.0414x over previous
//
#include <hip/hip_runtime.h>

#define S_TOK 8192
#define M_DIM 512
#define E_NUM 8
#define CAP   1024
#define H_DIM 1024
#define NGATE_BLK (S_TOK / 4)

typedef __attribute__((ext_vector_type(8))) short bf16x8;
typedef __attribute__((ext_vector_type(4))) float f32x4;

__device__ static inline unsigned short f2bf(float f) {
    unsigned int u = __float_as_uint(f);
    unsigned int r = (u + 0x7fffu + ((u >> 16) & 1u)) >> 16;
    return (unsigned short)r;
}

__device__ static inline void async_copy16(const void* g, void* l) {
    __builtin_amdgcn_global_load_lds(
        (const __attribute__((address_space(1))) void*)g,
        (__attribute__((address_space(3))) void*)l, 16, 0, 0);
}

// ---------------------------------------------------------------------------
// K1: gating + x->bf16 conversion, single pass over feats.
// One wave per token; each lane owns 8 consecutive elements.
// Emits per-block gate partial sums (for l_aux me) instead of per-token gates.
// ---------------------------------------------------------------------------
__global__ __launch_bounds__(256) void gate_kernel(
    const float* __restrict__ feats, const float* __restrict__ wg,
    int* __restrict__ idx, float* __restrict__ gate_top,
    float* __restrict__ gates_psum, unsigned short* __restrict__ xb)
{
    __shared__ float gsh[4][8];
    const int wave = threadIdx.x >> 6;
    const int lane = threadIdx.x & 63;
    const int s = blockIdx.x * 4 + wave;

    const float* xrow = feats + (size_t)s * M_DIM;
    const int m0 = lane * 8;

    const float4 va = *(const float4*)(xrow + m0);
    const float4 vb = *(const float4*)(xrow + m0 + 4);
    float xv[8] = {va.x, va.y, va.z, va.w, vb.x, vb.y, vb.z, vb.w};

    // bf16 store (one 16B store per lane); block 0 also zeroes sentinel row
    {
        bf16x8 o;
#pragma unroll
        for (int j = 0; j < 8; ++j) o[j] = (short)f2bf(xv[j]);
        *(bf16x8*)(xb + (size_t)s * M_DIM + m0) = o;
        if (blockIdx.x == 0 && wave == 0) {
            bf16x8 z = (bf16x8){0,0,0,0,0,0,0,0};
            *(bf16x8*)(xb + (size_t)S_TOK * M_DIM + m0) = z;
        }
    }

    float p[8];
#pragma unroll
    for (int e = 0; e < 8; ++e) p[e] = 0.f;
#pragma unroll
    for (int j = 0; j < 8; ++j) {
        const float4 wa = *(const float4*)(wg + (m0 + j) * 8);
        const float4 wb2 = *(const float4*)(wg + (m0 + j) * 8 + 4);
        const float x = xv[j];
        p[0] += x * wa.x;  p[1] += x * wa.y;  p[2] += x * wa.z;  p[3] += x * wa.w;
        p[4] += x * wb2.x; p[5] += x * wb2.y; p[6] += x * wb2.z; p[7] += x * wb2.w;
    }
#pragma unroll
    for (int e = 0; e < 8; ++e) {
        float v = p[e];
#pragma unroll
        for (int off = 1; off < 64; off <<= 1) v += __shfl_xor(v, off, 64);
        p[e] = v;
    }
    if (lane == 0) {
        float mx = p[0];
#pragma unroll
        for (int e = 1; e < 8; ++e) mx = fmaxf(mx, p[e]);
        float ex[8], sum = 0.f;
#pragma unroll
        for (int e = 0; e < 8; ++e) { ex[e] = expf(p[e] - mx); sum += ex[e]; }
        const float inv = 1.0f / sum;
        int best = 0; float bl = p[0];
#pragma unroll
        for (int e = 1; e < 8; ++e) { if (p[e] > bl) { bl = p[e]; best = e; } }
#pragma unroll
        for (int e = 0; e < 8; ++e) gsh[wave][e] = ex[e] * inv;
        idx[s] = best;
        gate_top[s] = ex[best] * inv;
    }
    __syncthreads();
    if (threadIdx.x < 8) {
        const int e = threadIdx.x;
        gates_psum[blockIdx.x * 8 + e] =
            gsh[0][e] + gsh[1][e] + gsh[2][e] + gsh[3][e];
    }
}

// ---------------------------------------------------------------------------
// K2: single-workgroup scan + capacity + token lists + l_aux + dropped list.
// ---------------------------------------------------------------------------
__global__ __launch_bounds__(256) void scan_kernel(
    const int* __restrict__ idx, const float* __restrict__ gate_top,
    const float* __restrict__ gates_psum,
    float* __restrict__ gate_final, int* __restrict__ token_list,
    int* __restrict__ kept, float* __restrict__ laux,
    int* __restrict__ dropped, int* __restrict__ ndrop)
{
    __shared__ int   cnts[256][8];
    __shared__ float msum[256][8];
    __shared__ int   totals[8];
    __shared__ float mesum[8];
    __shared__ int   dropctr;

    const int t = threadIdx.x;
    const int base = t * 32;

    for (int i = t; i < E_NUM * CAP; i += 256) token_list[i] = S_TOK;
    if (t == 0) dropctr = 0;

    int c[8];
#pragma unroll
    for (int e = 0; e < 8; ++e) c[e] = 0;
    for (int i = 0; i < 32; ++i) {
        const int ei = idx[base + i];
#pragma unroll
        for (int e = 0; e < 8; ++e) c[e] += (ei == e) ? 1 : 0;
    }

    // coalesced me-partials sum: thread t covers gate blocks t, t+256, ...
    float g[8];
#pragma unroll
    for (int e = 0; e < 8; ++e) g[e] = 0.f;
    for (int i = 0; i < NGATE_BLK / 256; ++i) {
        const float* gp = gates_psum + (size_t)(t + 256 * i) * 8;
        const float4 a = *(const float4*)gp;
        const float4 b = *(const float4*)(gp + 4);
        g[0] += a.x; g[1] += a.y; g[2] += a.z; g[3] += a.w;
        g[4] += b.x; g[5] += b.y; g[6] += b.z; g[7] += b.w;
    }
#pragma unroll
    for (int e = 0; e < 8; ++e) { cnts[t][e] = c[e]; msum[t][e] = g[e]; }
    __syncthreads();

    if (t < 8) {
        int run = 0; float ms = 0.f;
        for (int r = 0; r < 256; ++r) {
            const int v = cnts[r][t];
            cnts[r][t] = run;
            run += v;
            ms += msum[r][t];
        }
        totals[t] = run;
        mesum[t] = ms;
        kept[t] = run < CAP ? run : CAP;
    }
    __syncthreads();

    if (t == 0) {
        float l = 0.f;
        for (int e = 0; e < 8; ++e) {
            const int ke = totals[e] < CAP ? totals[e] : CAP;
            l += (mesum[e] / (float)S_TOK) * ((float)ke / (float)S_TOK);
        }
        laux[0] = l * (float)E_NUM;
    }

    int rc[8];
#pragma unroll
    for (int e = 0; e < 8; ++e) rc[e] = cnts[t][e];

    for (int i = 0; i < 32; ++i) {
        const int s = base + i;
        const int ei = idx[s];
        int loc = 0;
#pragma unroll
        for (int e = 0; e < 8; ++e) {
            if (ei == e) { loc = rc[e]; rc[e] = rc[e] + 1; }
        }
        const bool keepit = loc < CAP;
        gate_final[s] = keepit ? gate_top[s] : 0.f;
        if (keepit) {
            token_list[ei * CAP + loc] = s;
        } else {
            const int d = atomicAdd(&dropctr, 1);
            dropped[d] = s;
        }
    }
    __syncthreads();
    if (t == 0) ndrop[0] = dropctr;
}

// ---------------------------------------------------------------------------
// zero_dropped: zero out rows of dropped tokens.
// ---------------------------------------------------------------------------
__global__ __launch_bounds__(256) void zero_dropped(
    const int* __restrict__ dropped, const int* __restrict__ ndrop,
    float* __restrict__ out)
{
    const int n = ndrop[0];
    const int t = threadIdx.x;
    for (int d = blockIdx.x; d < n; d += gridDim.x) {
        const int s = dropped[d];
        *(float2*)(out + (size_t)s * M_DIM + t * 2) = make_float2(0.f, 0.f);
    }
}

// ---------------------------------------------------------------------------
// Weight convert+transpose (float4 loads / ushort4 stores):
//   w1 [8][512][1024] -> w1t [8][1024][512]
//   w2 [8][1024][512] -> w2t [8][512][1024]
// ---------------------------------------------------------------------------
__global__ __launch_bounds__(256) void convert_w(
    const float* __restrict__ w1, unsigned short* __restrict__ w1t,
    const float* __restrict__ w2, unsigned short* __restrict__ w2t)
{
    __shared__ float tile[32][33];
    int b = blockIdx.x;
    const float* src; unsigned short* dst;
    int e, k0, n0, K, N;
    if (b < 4096) {
        e = b >> 9; k0 = ((b >> 5) & 15) * 32; n0 = (b & 31) * 32;
        K = 512; N = 1024; src = w1; dst = w1t;
    } else {
        b -= 4096;
        e = b >> 9; k0 = ((b >> 4) & 31) * 32; n0 = (b & 15) * 32;
        K = 1024; N = 512; src = w2; dst = w2t;
    }
    const int t = threadIdx.x;
    const int r = t >> 3, c4 = (t & 7) * 4;
    {
        const float4 v = *(const float4*)(src + ((size_t)e * K + k0 + r) * N + n0 + c4);
        tile[r][c4 + 0] = v.x; tile[r][c4 + 1] = v.y;
        tile[r][c4 + 2] = v.z; tile[r][c4 + 3] = v.w;
    }
    __syncthreads();
    {
        ushort4 o;
        o.x = f2bf(tile[c4 + 0][r]); o.y = f2bf(tile[c4 + 1][r]);
        o.z = f2bf(tile[c4 + 2][r]); o.w = f2bf(tile[c4 + 3][r]);
        *(ushort4*)(dst + ((size_t)e * N + n0 + r) * K + k0 + c4) = o;
    }
}

// ---------------------------------------------------------------------------
// K3: MFMA grouped GEMM1 + bias + ReLU -> h (bf16).
// 128x128 tile, BK=64, double-buffered LDS, XOR-swizzled chunk layout
// (slot = row*8 + (ch ^ (row&7))) to spread ds_read_b128 across all 32 banks.
// Expert in LOW bits of blockIdx -> expert<->XCD affinity.
// ---------------------------------------------------------------------------
__global__ __launch_bounds__(256) void ffn1_mfma(
    const unsigned short* __restrict__ xb, const unsigned short* __restrict__ w1t,
    const float* __restrict__ b1, const int* __restrict__ tok,
    const int* __restrict__ kept, unsigned short* __restrict__ h)
{
    const int b = blockIdx.x;          // 512 = 8ct*8nt | 8e
    const int e = b & 7;
    const int r = b >> 3;
    const int ct = r >> 3, nt = r & 7;
    const int c0 = ct * 128, n0 = nt * 128;
    if (c0 >= kept[e]) return;

    __shared__ __align__(16) short Alds[2][128 * 64];
    __shared__ __align__(16) short Blds[2][128 * 64];
    __shared__ int srow[128];

    const int t = threadIdx.x;
    const int wave = t >> 6, lane = t & 63;
    const int wm = wave & 1, wn = wave >> 1;
    const int q = lane >> 4, lr = lane & 15;

    if (t < 128) srow[t] = tok[e * CAP + c0 + t];

    auto stage = [&](int buf, int kb) {
#pragma unroll
        for (int i = 0; i < 4; ++i) {
            const int lin = (i * 4 + wave) * 64 + lane;
            const int row = lin >> 3;
            const int ch = (lin & 7) ^ (row & 7);
            async_copy16(xb + (size_t)srow[row] * M_DIM + kb + ch * 8,
                         &Alds[buf][lin * 8]);
        }
#pragma unroll
        for (int i = 0; i < 4; ++i) {
            const int lin = (i * 4 + wave) * 64 + lane;
            const int row = lin >> 3;
            const int ch = (lin & 7) ^ (row & 7);
            async_copy16(w1t + ((size_t)e * H_DIM + n0 + row) * M_DIM + kb + ch * 8,
                         &Blds[buf][lin * 8]);
        }
    };

    f32x4 acc[4][4];
#pragma unroll
    for (int mi = 0; mi < 4; ++mi)
#pragma unroll
        for (int ni = 0; ni < 4; ++ni) acc[mi][ni] = (f32x4){0.f, 0.f, 0.f, 0.f};

    __syncthreads();            // srow visible
    stage(0, 0);

    int cur = 0;
    for (int kb = 0; kb < M_DIM; kb += 64) {
        __syncthreads();        // drains vmcnt: buf 'cur' ready; prev compute done
        if (kb + 64 < M_DIM) stage(cur ^ 1, kb + 64);

#pragma unroll
        for (int kk = 0; kk < 64; kk += 32) {
            const int cb = kk >> 3;
            bf16x8 af[4], bfv[4];
#pragma unroll
            for (int mi = 0; mi < 4; ++mi) {
                const int R = wm * 64 + mi * 16 + lr;
                af[mi] = *(const bf16x8*)(&Alds[cur][(R * 8 + ((cb + q) ^ (R & 7))) * 8]);
            }
#pragma unroll
            for (int ni = 0; ni < 4; ++ni) {
                const int R = wn * 64 + ni * 16 + lr;
                bfv[ni] = *(const bf16x8*)(&Blds[cur][(R * 8 + ((cb + q) ^ (R & 7))) * 8]);
            }
#pragma unroll
            for (int mi = 0; mi < 4; ++mi)
#pragma unroll
                for (int ni = 0; ni < 4; ++ni)
                    acc[mi][ni] = __builtin_amdgcn_mfma_f32_16x16x32_bf16(
                        af[mi], bfv[ni], acc[mi][ni], 0, 0, 0);
        }
        cur ^= 1;
    }

#pragma unroll
    for (int ni = 0; ni < 4; ++ni) {
        const int col = n0 + wn * 64 + ni * 16 + lr;
        const float bias = b1[e * H_DIM + col];
#pragma unroll
        for (int mi = 0; mi < 4; ++mi) {
            const int rowl = wm * 64 + mi * 16 + q * 4;
            const size_t basep = (size_t)(e * CAP + c0 + rowl) * H_DIM + col;
#pragma unroll
            for (int r2 = 0; r2 < 4; ++r2) {
                const float v = fmaxf(acc[mi][ni][r2] + bias, 0.f);
                h[basep + (size_t)r2 * H_DIM] = f2bf(v);
            }
        }
    }
}

// ---------------------------------------------------------------------------
// K4: MFMA grouped GEMM2 + bias + gate-scaled scatter. 128x64 tile, BK=64,
// double-buffered, swizzled. tok/gate preloaded to LDS for the epilogue.
// ---------------------------------------------------------------------------
__global__ __launch_bounds__(256) void ffn2_mfma(
    const unsigned short* __restrict__ h, const unsigned short* __restrict__ w2t,
    const float* __restrict__ b2, const int* __restrict__ tok,
    const int* __restrict__ kept, const float* __restrict__ gate_final,
    float* __restrict__ out)
{
    const int b = blockIdx.x;          // 512 = 8ct*8nt | 8e
    const int e = b & 7;
    const int r = b >> 3;
    const int ct = r >> 3, nt = r & 7;
    const int c0 = ct * 128, n0 = nt * 64;
    if (c0 >= kept[e]) return;

    __shared__ __align__(16) short Alds[2][128 * 64];
    __shared__ __align__(16) short Blds[2][64 * 64];
    __shared__ int   stok[128];
    __shared__ float sgf[128];

    const int t = threadIdx.x;
    const int wave = t >> 6, lane = t & 63;
    const int wm = wave & 1, wn = wave >> 1;
    const int q = lane >> 4, lr = lane & 15;

    if (t < 128) {
        const int tk = tok[e * CAP + c0 + t];
        stok[t] = tk;
        sgf[t] = (tk != S_TOK) ? gate_final[tk] : 0.f;
    }

    auto stage = [&](int buf, int kb) {
#pragma unroll
        for (int i = 0; i < 4; ++i) {
            const int lin = (i * 4 + wave) * 64 + lane;
            const int row = lin >> 3;
            const int ch = (lin & 7) ^ (row & 7);
            async_copy16(h + (size_t)(e * CAP + c0 + row) * H_DIM + kb + ch * 8,
                         &Alds[buf][lin * 8]);
        }
#pragma unroll
        for (int i = 0; i < 2; ++i) {
            const int lin = (i * 4 + wave) * 64 + lane;
            const int row = lin >> 3;
            const int ch = (lin & 7) ^ (row & 7);
            async_copy16(w2t + ((size_t)e * M_DIM + n0 + row) * H_DIM + kb + ch * 8,
                         &Blds[buf][lin * 8]);
        }
    };

    f32x4 acc[4][2];
#pragma unroll
    for (int mi = 0; mi < 4; ++mi)
#pragma unroll
        for (int ni = 0; ni < 2; ++ni) acc[mi][ni] = (f32x4){0.f, 0.f, 0.f, 0.f};

    __syncthreads();
    stage(0, 0);

    int cur = 0;
    for (int kb = 0; kb < H_DIM; kb += 64) {
        __syncthreads();
        if (kb + 64 < H_DIM) stage(cur ^ 1, kb + 64);

#pragma unroll
        for (int kk = 0; kk < 64; kk += 32) {
            const int cb = kk >> 3;
            bf16x8 af[4], bfv[2];
#pragma unroll
            for (int mi = 0; mi < 4; ++mi) {
                const int R = wm * 64 + mi * 16 + lr;
                af[mi] = *(const bf16x8*)(&Alds[cur][(R * 8 + ((cb + q) ^ (R & 7))) * 8]);
            }
#pragma unroll
            for (int ni = 0; ni < 2; ++ni) {
                const int R = wn * 32 + ni * 16 + lr;
                bfv[ni] = *(const bf16x8*)(&Blds[cur][(R * 8 + ((cb + q) ^ (R & 7))) * 8]);
            }
#pragma unroll
            for (int mi = 0; mi < 4; ++mi)
#pragma unroll
                for (int ni = 0; ni < 2; ++ni)
                    acc[mi][ni] = __builtin_amdgcn_mfma_f32_16x16x32_bf16(
                        af[mi], bfv[ni], acc[mi][ni], 0, 0, 0);
        }
        cur ^= 1;
    }

#pragma unroll
    for (int ni = 0; ni < 2; ++ni) {
        const int col = n0 + wn * 32 + ni * 16 + lr;
        const float bias = b2[e * M_DIM + col];
#pragma unroll
        for (int mi = 0; mi < 4; ++mi) {
            const int rowl = wm * 64 + mi * 16 + q * 4;
#pragma unroll
            for (int r2 = 0; r2 < 4; ++r2) {
                const int slot = rowl + r2;
                const int tokid = stok[slot];
                if (tokid != S_TOK) {
                    out[(size_t)tokid * M_DIM + col] = sgf[slot] * (acc[mi][ni][r2] + bias);
                }
            }
        }
    }
}

// ---------------------------------------------------------------------------
extern "C" void kernel_launch(void* const* d_in, const int* in_sizes, int n_in,
                              void* d_out, int out_size, void* d_ws, size_t ws_size,
                              hipStream_t stream) {
    const float* feats = (const float*)d_in[0];
    const float* wg    = (const float*)d_in[1];
    const float* w1    = (const float*)d_in[2];
    const float* b1    = (const float*)d_in[3];
    const float* w2    = (const float*)d_in[4];
    const float* b2    = (const float*)d_in[5];
    float* out = (float*)d_out;

    char* ws = (char*)d_ws;
    size_t off = 0;
    unsigned short* h   = (unsigned short*)(ws + off); off += (size_t)E_NUM * CAP * H_DIM * 2;
    unsigned short* xb  = (unsigned short*)(ws + off); off += (size_t)(S_TOK + 1) * M_DIM * 2;
    unsigned short* w1t = (unsigned short*)(ws + off); off += (size_t)E_NUM * H_DIM * M_DIM * 2;
    unsigned short* w2t = (unsigned short*)(ws + off); off += (size_t)E_NUM * M_DIM * H_DIM * 2;
    int*   idx        = (int*)(ws + off);   off += (size_t)S_TOK * 4;
    float* gate_top   = (float*)(ws + off); off += (size_t)S_TOK * 4;
    float* gate_final = (float*)(ws + off); off += (size_t)S_TOK * 4;
    float* gates_psum = (float*)(ws + off); off += (size_t)NGATE_BLK * 8 * 4;
    int*   token_list = (int*)(ws + off);   off += (size_t)S_TOK * 4;
    int*   dropped    = (int*)(ws + off);   off += (size_t)S_TOK * 4;
    int*   kept       = (int*)(ws + off);   off += 64;
    int*   ndrop      = (int*)(ws + off);   off += 64;
    (void)ws_size; (void)n_in; (void)in_sizes;

    gate_kernel<<<NGATE_BLK, 256, 0, stream>>>(feats, wg, idx, gate_top,
                                               gates_psum, xb);
    convert_w<<<8192, 256, 0, stream>>>(w1, w1t, w2, w2t);
    scan_kernel<<<1, 256, 0, stream>>>(idx, gate_top, gates_psum, gate_final,
                                       token_list, kept, out + (size_t)S_TOK * M_DIM,
                                       dropped, ndrop);
    zero_dropped<<<256, 256, 0, stream>>>(dropped, ndrop, out);
    ffn1_mfma<<<512, 256, 0, stream>>>(xb, w1t, b1, token_list, kept, h);
    ffn2_mfma<<<512, 256, 0, stream>>>(h, w2t, b2, token_list, kept,
                                       gate_final, out);
}

// Round 5
// 180.600 us; speedup vs baseline: 2.5946x; 1.0304x over previous
//
#include <hip/hip_runtime.h>

#define S_TOK 8192
#define M_DIM 512
#define E_NUM 8
#define CAP   1024
#define H_DIM 1024
#define NGATE_BLK (S_TOK / 4)

typedef __attribute__((ext_vector_type(8))) short bf16x8;
typedef __attribute__((ext_vector_type(4))) float f32x4;

__device__ static inline unsigned short f2bf(float f) {
    unsigned int u = __float_as_uint(f);
    unsigned int r = (u + 0x7fffu + ((u >> 16) & 1u)) >> 16;
    return (unsigned short)r;
}

__device__ static inline void async_copy16(const void* g, void* l) {
    __builtin_amdgcn_global_load_lds(
        (const __attribute__((address_space(1))) void*)g,
        (__attribute__((address_space(3))) void*)l, 16, 0, 0);
}

// ---------------------------------------------------------------------------
// K1: gating + x->bf16 conversion, single pass over feats.
// ---------------------------------------------------------------------------
__global__ __launch_bounds__(256) void gate_kernel(
    const float* __restrict__ feats, const float* __restrict__ wg,
    int* __restrict__ idx, float* __restrict__ gate_top,
    float* __restrict__ gates_psum, unsigned short* __restrict__ xb)
{
    __shared__ float gsh[4][8];
    const int wave = threadIdx.x >> 6;
    const int lane = threadIdx.x & 63;
    const int s = blockIdx.x * 4 + wave;

    const float* xrow = feats + (size_t)s * M_DIM;
    const int m0 = lane * 8;

    const float4 va = *(const float4*)(xrow + m0);
    const float4 vb = *(const float4*)(xrow + m0 + 4);
    float xv[8] = {va.x, va.y, va.z, va.w, vb.x, vb.y, vb.z, vb.w};

    {
        bf16x8 o;
#pragma unroll
        for (int j = 0; j < 8; ++j) o[j] = (short)f2bf(xv[j]);
        *(bf16x8*)(xb + (size_t)s * M_DIM + m0) = o;
        if (blockIdx.x == 0 && wave == 0) {
            bf16x8 z = (bf16x8){0,0,0,0,0,0,0,0};
            *(bf16x8*)(xb + (size_t)S_TOK * M_DIM + m0) = z;
        }
    }

    float p[8];
#pragma unroll
    for (int e = 0; e < 8; ++e) p[e] = 0.f;
#pragma unroll
    for (int j = 0; j < 8; ++j) {
        const float4 wa = *(const float4*)(wg + (m0 + j) * 8);
        const float4 wb2 = *(const float4*)(wg + (m0 + j) * 8 + 4);
        const float x = xv[j];
        p[0] += x * wa.x;  p[1] += x * wa.y;  p[2] += x * wa.z;  p[3] += x * wa.w;
        p[4] += x * wb2.x; p[5] += x * wb2.y; p[6] += x * wb2.z; p[7] += x * wb2.w;
    }
#pragma unroll
    for (int e = 0; e < 8; ++e) {
        float v = p[e];
#pragma unroll
        for (int off = 1; off < 64; off <<= 1) v += __shfl_xor(v, off, 64);
        p[e] = v;
    }
    if (lane == 0) {
        float mx = p[0];
#pragma unroll
        for (int e = 1; e < 8; ++e) mx = fmaxf(mx, p[e]);
        float ex[8], sum = 0.f;
#pragma unroll
        for (int e = 0; e < 8; ++e) { ex[e] = expf(p[e] - mx); sum += ex[e]; }
        const float inv = 1.0f / sum;
        int best = 0; float bl = p[0];
#pragma unroll
        for (int e = 1; e < 8; ++e) { if (p[e] > bl) { bl = p[e]; best = e; } }
#pragma unroll
        for (int e = 0; e < 8; ++e) gsh[wave][e] = ex[e] * inv;
        idx[s] = best;
        gate_top[s] = ex[best] * inv;
    }
    __syncthreads();
    if (threadIdx.x < 8) {
        const int e = threadIdx.x;
        gates_psum[blockIdx.x * 8 + e] =
            gsh[0][e] + gsh[1][e] + gsh[2][e] + gsh[3][e];
    }
}

// ---------------------------------------------------------------------------
// K2: single-workgroup scan. Parallel wave-level prefix scan replaces the
// serial 256-iteration chain. Also zeroes dropped-token out rows (merged).
// ---------------------------------------------------------------------------
__global__ __launch_bounds__(256) void scan_kernel(
    const int* __restrict__ idx, const float* __restrict__ gate_top,
    const float* __restrict__ gates_psum,
    float* __restrict__ gate_final, int* __restrict__ token_list,
    int* __restrict__ kept, float* __restrict__ out)
{
    __shared__ int   cnts[256][9];   // +1 pad: stride 9 breaks bank aliasing
    __shared__ float wpart[4][8];
    __shared__ int   totals[8];
    __shared__ int   sdrop[7168];
    __shared__ int   dropctr;

    const int t = threadIdx.x;
    const int wv = t >> 6, ln = t & 63;
    const int base = t * 32;

    for (int i = t; i < E_NUM * CAP; i += 256) token_list[i] = S_TOK;
    if (t == 0) dropctr = 0;

    // phase A: per-chunk counts + gates partial sums
    int c[8];
#pragma unroll
    for (int e = 0; e < 8; ++e) c[e] = 0;
    for (int i = 0; i < 32; ++i) {
        const int ei = idx[base + i];
#pragma unroll
        for (int e = 0; e < 8; ++e) c[e] += (ei == e) ? 1 : 0;
    }
    float g[8];
#pragma unroll
    for (int e = 0; e < 8; ++e) g[e] = 0.f;
    for (int i = 0; i < NGATE_BLK / 256; ++i) {
        const float* gp = gates_psum + (size_t)(t + 256 * i) * 8;
        const float4 a = *(const float4*)gp;
        const float4 b = *(const float4*)(gp + 4);
        g[0] += a.x; g[1] += a.y; g[2] += a.z; g[3] += a.w;
        g[4] += b.x; g[5] += b.y; g[6] += b.z; g[7] += b.w;
    }
#pragma unroll
    for (int e = 0; e < 8; ++e) cnts[t][e] = c[e];
#pragma unroll
    for (int e = 0; e < 8; ++e) {
        float v = g[e];
#pragma unroll
        for (int off = 1; off < 64; off <<= 1) v += __shfl_xor(v, off, 64);
        if (ln == 0) wpart[wv][e] = v;
    }
    __syncthreads();

    // phase B: parallel exclusive scan over 256 chunks; wave wv owns 2 experts
#pragma unroll
    for (int ee = 0; ee < 2; ++ee) {
        const int e = wv * 2 + ee;
        int off = 0;
#pragma unroll
        for (int seg = 0; seg < 4; ++seg) {
            const int r = seg * 64 + ln;
            const int v = cnts[r][e];
            int incl = v;
#pragma unroll
            for (int d = 1; d < 64; d <<= 1) {
                const int nn = __shfl_up(incl, d, 64);
                if (ln >= d) incl += nn;
            }
            cnts[r][e] = incl - v + off;
            off += __shfl(incl, 63, 64);
        }
        if (ln == 0) {
            totals[e] = off;
            kept[e] = off < CAP ? off : CAP;
        }
    }
    __syncthreads();

    if (t == 0) {
        float l = 0.f;
        for (int e = 0; e < 8; ++e) {
            const float ms = wpart[0][e] + wpart[1][e] + wpart[2][e] + wpart[3][e];
            const int ke = totals[e] < CAP ? totals[e] : CAP;
            l += (ms / (float)S_TOK) * ((float)ke / (float)S_TOK);
        }
        out[(size_t)S_TOK * M_DIM] = l * (float)E_NUM;   // l_aux
    }

    // phase C: arrival-order slot assignment + drop collection
    int rc[8];
#pragma unroll
    for (int e = 0; e < 8; ++e) rc[e] = cnts[t][e];

    for (int i = 0; i < 32; ++i) {
        const int s = base + i;
        const int ei = idx[s];
        int loc = 0;
#pragma unroll
        for (int e = 0; e < 8; ++e) {
            if (ei == e) { loc = rc[e]; rc[e] = rc[e] + 1; }
        }
        const bool keepit = loc < CAP;
        gate_final[s] = keepit ? gate_top[s] : 0.f;
        if (keepit) {
            token_list[ei * CAP + loc] = s;
        } else {
            const int d = atomicAdd(&dropctr, 1);
            sdrop[d] = s;
        }
    }
    __syncthreads();

    // zero dropped rows cooperatively (256 threads x float2 = 512 floats/row)
    const int nd = dropctr;
    for (int d = 0; d < nd; ++d) {
        const int s = sdrop[d];
        *(float2*)(out + (size_t)s * M_DIM + t * 2) = make_float2(0.f, 0.f);
    }
}

// ---------------------------------------------------------------------------
// Weight convert+transpose (float4 loads / ushort4 stores).
// ---------------------------------------------------------------------------
__global__ __launch_bounds__(256) void convert_w(
    const float* __restrict__ w1, unsigned short* __restrict__ w1t,
    const float* __restrict__ w2, unsigned short* __restrict__ w2t)
{
    __shared__ float tile[32][33];
    int b = blockIdx.x;
    const float* src; unsigned short* dst;
    int e, k0, n0, K, N;
    if (b < 4096) {
        e = b >> 9; k0 = ((b >> 5) & 15) * 32; n0 = (b & 31) * 32;
        K = 512; N = 1024; src = w1; dst = w1t;
    } else {
        b -= 4096;
        e = b >> 9; k0 = ((b >> 4) & 31) * 32; n0 = (b & 15) * 32;
        K = 1024; N = 512; src = w2; dst = w2t;
    }
    const int t = threadIdx.x;
    const int r = t >> 3, c4 = (t & 7) * 4;
    {
        const float4 v = *(const float4*)(src + ((size_t)e * K + k0 + r) * N + n0 + c4);
        tile[r][c4 + 0] = v.x; tile[r][c4 + 1] = v.y;
        tile[r][c4 + 2] = v.z; tile[r][c4 + 3] = v.w;
    }
    __syncthreads();
    {
        ushort4 o;
        o.x = f2bf(tile[c4 + 0][r]); o.y = f2bf(tile[c4 + 1][r]);
        o.z = f2bf(tile[c4 + 2][r]); o.w = f2bf(tile[c4 + 3][r]);
        *(ushort4*)(dst + ((size_t)e * N + n0 + r) * K + k0 + c4) = o;
    }
}

// ---------------------------------------------------------------------------
// K3: MFMA grouped GEMM1 + bias + ReLU -> h (bf16). (unchanged control)
// 128x128 tile, BK=64, double-buffered, XOR-swizzled.
// ---------------------------------------------------------------------------
__global__ __launch_bounds__(256) void ffn1_mfma(
    const unsigned short* __restrict__ xb, const unsigned short* __restrict__ w1t,
    const float* __restrict__ b1, const int* __restrict__ tok,
    const int* __restrict__ kept, unsigned short* __restrict__ h)
{
    const int b = blockIdx.x;          // 512 = 8ct*8nt | 8e
    const int e = b & 7;
    const int r = b >> 3;
    const int ct = r >> 3, nt = r & 7;
    const int c0 = ct * 128, n0 = nt * 128;
    if (c0 >= kept[e]) return;

    __shared__ __align__(16) short Alds[2][128 * 64];
    __shared__ __align__(16) short Blds[2][128 * 64];
    __shared__ int srow[128];

    const int t = threadIdx.x;
    const int wave = t >> 6, lane = t & 63;
    const int wm = wave & 1, wn = wave >> 1;
    const int q = lane >> 4, lr = lane & 15;

    if (t < 128) srow[t] = tok[e * CAP + c0 + t];

    auto stage = [&](int buf, int kb) {
#pragma unroll
        for (int i = 0; i < 4; ++i) {
            const int lin = (i * 4 + wave) * 64 + lane;
            const int row = lin >> 3;
            const int ch = (lin & 7) ^ (row & 7);
            async_copy16(xb + (size_t)srow[row] * M_DIM + kb + ch * 8,
                         &Alds[buf][lin * 8]);
        }
#pragma unroll
        for (int i = 0; i < 4; ++i) {
            const int lin = (i * 4 + wave) * 64 + lane;
            const int row = lin >> 3;
            const int ch = (lin & 7) ^ (row & 7);
            async_copy16(w1t + ((size_t)e * H_DIM + n0 + row) * M_DIM + kb + ch * 8,
                         &Blds[buf][lin * 8]);
        }
    };

    f32x4 acc[4][4];
#pragma unroll
    for (int mi = 0; mi < 4; ++mi)
#pragma unroll
        for (int ni = 0; ni < 4; ++ni) acc[mi][ni] = (f32x4){0.f, 0.f, 0.f, 0.f};

    __syncthreads();
    stage(0, 0);

    int cur = 0;
    for (int kb = 0; kb < M_DIM; kb += 64) {
        __syncthreads();
        if (kb + 64 < M_DIM) stage(cur ^ 1, kb + 64);

#pragma unroll
        for (int kk = 0; kk < 64; kk += 32) {
            const int cb = kk >> 3;
            bf16x8 af[4], bfv[4];
#pragma unroll
            for (int mi = 0; mi < 4; ++mi) {
                const int R = wm * 64 + mi * 16 + lr;
                af[mi] = *(const bf16x8*)(&Alds[cur][(R * 8 + ((cb + q) ^ (R & 7))) * 8]);
            }
#pragma unroll
            for (int ni = 0; ni < 4; ++ni) {
                const int R = wn * 64 + ni * 16 + lr;
                bfv[ni] = *(const bf16x8*)(&Blds[cur][(R * 8 + ((cb + q) ^ (R & 7))) * 8]);
            }
#pragma unroll
            for (int mi = 0; mi < 4; ++mi)
#pragma unroll
                for (int ni = 0; ni < 4; ++ni)
                    acc[mi][ni] = __builtin_amdgcn_mfma_f32_16x16x32_bf16(
                        af[mi], bfv[ni], acc[mi][ni], 0, 0, 0);
        }
        cur ^= 1;
    }

#pragma unroll
    for (int ni = 0; ni < 4; ++ni) {
        const int col = n0 + wn * 64 + ni * 16 + lr;
        const float bias = b1[e * H_DIM + col];
#pragma unroll
        for (int mi = 0; mi < 4; ++mi) {
            const int rowl = wm * 64 + mi * 16 + q * 4;
            const size_t basep = (size_t)(e * CAP + c0 + rowl) * H_DIM + col;
#pragma unroll
            for (int r2 = 0; r2 < 4; ++r2) {
                const float v = fmaxf(acc[mi][ni][r2] + bias, 0.f);
                h[basep + (size_t)r2 * H_DIM] = f2bf(v);
            }
        }
    }
}

// ---------------------------------------------------------------------------
// K4: MFMA grouped GEMM2, re-tiled 64x64 for occupancy: 1024 blocks ->
// 4 blocks/CU, 16 waves/CU. Single-buffer (16.25 KB LDS), swizzled.
// ---------------------------------------------------------------------------
__global__ __launch_bounds__(256) void ffn2_mfma(
    const unsigned short* __restrict__ h, const unsigned short* __restrict__ w2t,
    const float* __restrict__ b2, const int* __restrict__ tok,
    const int* __restrict__ kept, const float* __restrict__ gate_final,
    float* __restrict__ out)
{
    const int b = blockIdx.x;          // 1024 = (16ct*8nt) | 8e
    const int e = b & 7;
    const int r = b >> 3;
    const int ct = r >> 3, nt = r & 7;
    const int c0 = ct * 64, n0 = nt * 64;
    if (c0 >= kept[e]) return;

    __shared__ __align__(16) short Alds[64 * 64];
    __shared__ __align__(16) short Blds[64 * 64];
    __shared__ int   stok[64];
    __shared__ float sgf[64];

    const int t = threadIdx.x;
    const int wave = t >> 6, lane = t & 63;
    const int wm = wave & 1, wn = wave >> 1;
    const int q = lane >> 4, lr = lane & 15;

    if (t < 64) {
        const int tk = tok[e * CAP + c0 + t];
        stok[t] = tk;
        sgf[t] = (tk != S_TOK) ? gate_final[tk] : 0.f;
    }

    f32x4 acc[2][2];
#pragma unroll
    for (int mi = 0; mi < 2; ++mi)
#pragma unroll
        for (int ni = 0; ni < 2; ++ni) acc[mi][ni] = (f32x4){0.f, 0.f, 0.f, 0.f};

    for (int kb = 0; kb < H_DIM; kb += 64) {
        __syncthreads();
#pragma unroll
        for (int i = 0; i < 2; ++i) {
            const int lin = (i * 4 + wave) * 64 + lane;
            const int row = lin >> 3;
            const int ch = (lin & 7) ^ (row & 7);
            async_copy16(h + (size_t)(e * CAP + c0 + row) * H_DIM + kb + ch * 8,
                         &Alds[lin * 8]);
        }
#pragma unroll
        for (int i = 0; i < 2; ++i) {
            const int lin = (i * 4 + wave) * 64 + lane;
            const int row = lin >> 3;
            const int ch = (lin & 7) ^ (row & 7);
            async_copy16(w2t + ((size_t)e * M_DIM + n0 + row) * H_DIM + kb + ch * 8,
                         &Blds[lin * 8]);
        }
        __syncthreads();

#pragma unroll
        for (int kk = 0; kk < 64; kk += 32) {
            const int cb = kk >> 3;
            bf16x8 af[2], bfv[2];
#pragma unroll
            for (int mi = 0; mi < 2; ++mi) {
                const int R = wm * 32 + mi * 16 + lr;
                af[mi] = *(const bf16x8*)(&Alds[(R * 8 + ((cb + q) ^ (R & 7))) * 8]);
            }
#pragma unroll
            for (int ni = 0; ni < 2; ++ni) {
                const int R = wn * 32 + ni * 16 + lr;
                bfv[ni] = *(const bf16x8*)(&Blds[(R * 8 + ((cb + q) ^ (R & 7))) * 8]);
            }
#pragma unroll
            for (int mi = 0; mi < 2; ++mi)
#pragma unroll
                for (int ni = 0; ni < 2; ++ni)
                    acc[mi][ni] = __builtin_amdgcn_mfma_f32_16x16x32_bf16(
                        af[mi], bfv[ni], acc[mi][ni], 0, 0, 0);
        }
    }

#pragma unroll
    for (int ni = 0; ni < 2; ++ni) {
        const int col = n0 + wn * 32 + ni * 16 + lr;
        const float bias = b2[e * M_DIM + col];
#pragma unroll
        for (int mi = 0; mi < 2; ++mi) {
            const int rowl = wm * 32 + mi * 16 + q * 4;
#pragma unroll
            for (int r2 = 0; r2 < 4; ++r2) {
                const int slot = rowl + r2;
                const int tokid = stok[slot];
                if (tokid != S_TOK) {
                    out[(size_t)tokid * M_DIM + col] = sgf[slot] * (acc[mi][ni][r2] + bias);
                }
            }
        }
    }
}

// ---------------------------------------------------------------------------
extern "C" void kernel_launch(void* const* d_in, const int* in_sizes, int n_in,
                              void* d_out, int out_size, void* d_ws, size_t ws_size,
                              hipStream_t stream) {
    const float* feats = (const float*)d_in[0];
    const float* wg    = (const float*)d_in[1];
    const float* w1    = (const float*)d_in[2];
    const float* b1    = (const float*)d_in[3];
    const float* w2    = (const float*)d_in[4];
    const float* b2    = (const float*)d_in[5];
    float* out = (float*)d_out;

    char* ws = (char*)d_ws;
    size_t off = 0;
    unsigned short* h   = (unsigned short*)(ws + off); off += (size_t)E_NUM * CAP * H_DIM * 2;
    unsigned short* xb  = (unsigned short*)(ws + off); off += (size_t)(S_TOK + 1) * M_DIM * 2;
    unsigned short* w1t = (unsigned short*)(ws + off); off += (size_t)E_NUM * H_DIM * M_DIM * 2;
    unsigned short* w2t = (unsigned short*)(ws + off); off += (size_t)E_NUM * M_DIM * H_DIM * 2;
    int*   idx        = (int*)(ws + off);   off += (size_t)S_TOK * 4;
    float* gate_top   = (float*)(ws + off); off += (size_t)S_TOK * 4;
    float* gate_final = (float*)(ws + off); off += (size_t)S_TOK * 4;
    float* gates_psum = (float*)(ws + off); off += (size_t)NGATE_BLK * 8 * 4;
    int*   token_list = (int*)(ws + off);   off += (size_t)S_TOK * 4;
    int*   kept       = (int*)(ws + off);   off += 64;
    (void)ws_size; (void)n_in; (void)in_sizes;

    gate_kernel<<<NGATE_BLK, 256, 0, stream>>>(feats, wg, idx, gate_top,
                                               gates_psum, xb);
    convert_w<<<8192, 256, 0, stream>>>(w1, w1t, w2, w2t);
    scan_kernel<<<1, 256, 0, stream>>>(idx, gate_top, gates_psum, gate_final,
                                       token_list, kept, out);
    ffn1_mfma<<<512, 256, 0, stream>>>(xb, w1t, b1, token_list, kept, h);
    ffn2_mfma<<<1024, 256, 0, stream>>>(h, w2t, b2, token_list, kept,
                                        gate_final, out);
}

// Round 6
// 179.487 us; speedup vs baseline: 2.6107x; 1.0062x over previous
//
#include <hip/hip_runtime.h>

#define S_TOK 8192
#define M_DIM 512
#define E_NUM 8
#define CAP   1024
#define H_DIM 1024
#define NGATE_BLK (S_TOK / 4)

typedef __attribute__((ext_vector_type(8))) short bf16x8;
typedef __attribute__((ext_vector_type(4))) float f32x4;

__device__ static inline unsigned short f2bf(float f) {
    unsigned int u = __float_as_uint(f);
    unsigned int r = (u + 0x7fffu + ((u >> 16) & 1u)) >> 16;
    return (unsigned short)r;
}

__device__ static inline void async_copy16(const void* g, void* l) {
    __builtin_amdgcn_global_load_lds(
        (const __attribute__((address_space(1))) void*)g,
        (__attribute__((address_space(3))) void*)l, 16, 0, 0);
}

// ---------------------------------------------------------------------------
// K1 "prep": fused gating (+x->bf16) and weight convert/transpose.
// blocks [0,2048): gate, one wave per token.
// blocks [2048,10240): w1/w2 fp32->bf16 transpose.
// ---------------------------------------------------------------------------
__global__ __launch_bounds__(256) void prep_kernel(
    const float* __restrict__ feats, const float* __restrict__ wg,
    int* __restrict__ idx, float* __restrict__ gate_top,
    float* __restrict__ gates_psum, unsigned short* __restrict__ xb,
    const float* __restrict__ w1, unsigned short* __restrict__ w1t,
    const float* __restrict__ w2, unsigned short* __restrict__ w2t)
{
    __shared__ float gsh[4][8];
    __shared__ float tile[32][33];

    if (blockIdx.x < NGATE_BLK) {
        // ---------------- gate part ----------------
        const int wave = threadIdx.x >> 6;
        const int lane = threadIdx.x & 63;
        const int s = blockIdx.x * 4 + wave;

        const float* xrow = feats + (size_t)s * M_DIM;
        const int m0 = lane * 8;

        const float4 va = *(const float4*)(xrow + m0);
        const float4 vb = *(const float4*)(xrow + m0 + 4);
        float xv[8] = {va.x, va.y, va.z, va.w, vb.x, vb.y, vb.z, vb.w};

        {
            bf16x8 o;
#pragma unroll
            for (int j = 0; j < 8; ++j) o[j] = (short)f2bf(xv[j]);
            *(bf16x8*)(xb + (size_t)s * M_DIM + m0) = o;
            if (blockIdx.x == 0 && wave == 0) {
                bf16x8 z = (bf16x8){0,0,0,0,0,0,0,0};
                *(bf16x8*)(xb + (size_t)S_TOK * M_DIM + m0) = z;
            }
        }

        float p[8];
#pragma unroll
        for (int e = 0; e < 8; ++e) p[e] = 0.f;
#pragma unroll
        for (int j = 0; j < 8; ++j) {
            const float4 wa = *(const float4*)(wg + (m0 + j) * 8);
            const float4 wb2 = *(const float4*)(wg + (m0 + j) * 8 + 4);
            const float x = xv[j];
            p[0] += x * wa.x;  p[1] += x * wa.y;  p[2] += x * wa.z;  p[3] += x * wa.w;
            p[4] += x * wb2.x; p[5] += x * wb2.y; p[6] += x * wb2.z; p[7] += x * wb2.w;
        }
#pragma unroll
        for (int e = 0; e < 8; ++e) {
            float v = p[e];
#pragma unroll
            for (int off = 1; off < 64; off <<= 1) v += __shfl_xor(v, off, 64);
            p[e] = v;
        }
        if (lane == 0) {
            float mx = p[0];
#pragma unroll
            for (int e = 1; e < 8; ++e) mx = fmaxf(mx, p[e]);
            float ex[8], sum = 0.f;
#pragma unroll
            for (int e = 0; e < 8; ++e) { ex[e] = expf(p[e] - mx); sum += ex[e]; }
            const float inv = 1.0f / sum;
            int best = 0; float bl = p[0];
#pragma unroll
            for (int e = 1; e < 8; ++e) { if (p[e] > bl) { bl = p[e]; best = e; } }
#pragma unroll
            for (int e = 0; e < 8; ++e) gsh[wave][e] = ex[e] * inv;
            idx[s] = best;
            gate_top[s] = ex[best] * inv;
        }
        __syncthreads();
        if (threadIdx.x < 8) {
            const int e = threadIdx.x;
            gates_psum[blockIdx.x * 8 + e] =
                gsh[0][e] + gsh[1][e] + gsh[2][e] + gsh[3][e];
        }
    } else {
        // ---------------- weight convert part ----------------
        int b = blockIdx.x - NGATE_BLK;
        const float* src; unsigned short* dst;
        int e, k0, n0, K, N;
        if (b < 4096) {
            e = b >> 9; k0 = ((b >> 5) & 15) * 32; n0 = (b & 31) * 32;
            K = 512; N = 1024; src = w1; dst = w1t;
        } else {
            b -= 4096;
            e = b >> 9; k0 = ((b >> 4) & 31) * 32; n0 = (b & 15) * 32;
            K = 1024; N = 512; src = w2; dst = w2t;
        }
        const int t = threadIdx.x;
        const int r = t >> 3, c4 = (t & 7) * 4;
        {
            const float4 v = *(const float4*)(src + ((size_t)e * K + k0 + r) * N + n0 + c4);
            tile[r][c4 + 0] = v.x; tile[r][c4 + 1] = v.y;
            tile[r][c4 + 2] = v.z; tile[r][c4 + 3] = v.w;
        }
        __syncthreads();
        {
            ushort4 o;
            o.x = f2bf(tile[c4 + 0][r]); o.y = f2bf(tile[c4 + 1][r]);
            o.z = f2bf(tile[c4 + 2][r]); o.w = f2bf(tile[c4 + 3][r]);
            *(ushort4*)(dst + ((size_t)e * N + n0 + r) * K + k0 + c4) = o;
        }
    }
}

// ---------------------------------------------------------------------------
// K2: single-workgroup scan (parallel prefix) + capacity + token lists +
// l_aux + zero dropped out rows.
// ---------------------------------------------------------------------------
__global__ __launch_bounds__(256) void scan_kernel(
    const int* __restrict__ idx, const float* __restrict__ gate_top,
    const float* __restrict__ gates_psum,
    float* __restrict__ gate_final, int* __restrict__ token_list,
    int* __restrict__ kept, float* __restrict__ out)
{
    __shared__ int   cnts[256][9];
    __shared__ float wpart[4][8];
    __shared__ int   totals[8];
    __shared__ int   sdrop[7168];
    __shared__ int   dropctr;

    const int t = threadIdx.x;
    const int wv = t >> 6, ln = t & 63;
    const int base = t * 32;

    for (int i = t; i < E_NUM * CAP; i += 256) token_list[i] = S_TOK;
    if (t == 0) dropctr = 0;

    int c[8];
#pragma unroll
    for (int e = 0; e < 8; ++e) c[e] = 0;
    for (int i = 0; i < 32; ++i) {
        const int ei = idx[base + i];
#pragma unroll
        for (int e = 0; e < 8; ++e) c[e] += (ei == e) ? 1 : 0;
    }
    float g[8];
#pragma unroll
    for (int e = 0; e < 8; ++e) g[e] = 0.f;
    for (int i = 0; i < NGATE_BLK / 256; ++i) {
        const float* gp = gates_psum + (size_t)(t + 256 * i) * 8;
        const float4 a = *(const float4*)gp;
        const float4 b = *(const float4*)(gp + 4);
        g[0] += a.x; g[1] += a.y; g[2] += a.z; g[3] += a.w;
        g[4] += b.x; g[5] += b.y; g[6] += b.z; g[7] += b.w;
    }
#pragma unroll
    for (int e = 0; e < 8; ++e) cnts[t][e] = c[e];
#pragma unroll
    for (int e = 0; e < 8; ++e) {
        float v = g[e];
#pragma unroll
        for (int off = 1; off < 64; off <<= 1) v += __shfl_xor(v, off, 64);
        if (ln == 0) wpart[wv][e] = v;
    }
    __syncthreads();

#pragma unroll
    for (int ee = 0; ee < 2; ++ee) {
        const int e = wv * 2 + ee;
        int off = 0;
#pragma unroll
        for (int seg = 0; seg < 4; ++seg) {
            const int r = seg * 64 + ln;
            const int v = cnts[r][e];
            int incl = v;
#pragma unroll
            for (int d = 1; d < 64; d <<= 1) {
                const int nn = __shfl_up(incl, d, 64);
                if (ln >= d) incl += nn;
            }
            cnts[r][e] = incl - v + off;
            off += __shfl(incl, 63, 64);
        }
        if (ln == 0) {
            totals[e] = off;
            kept[e] = off < CAP ? off : CAP;
        }
    }
    __syncthreads();

    if (t == 0) {
        float l = 0.f;
        for (int e = 0; e < 8; ++e) {
            const float ms = wpart[0][e] + wpart[1][e] + wpart[2][e] + wpart[3][e];
            const int ke = totals[e] < CAP ? totals[e] : CAP;
            l += (ms / (float)S_TOK) * ((float)ke / (float)S_TOK);
        }
        out[(size_t)S_TOK * M_DIM] = l * (float)E_NUM;
    }

    int rc[8];
#pragma unroll
    for (int e = 0; e < 8; ++e) rc[e] = cnts[t][e];

    for (int i = 0; i < 32; ++i) {
        const int s = base + i;
        const int ei = idx[s];
        int loc = 0;
#pragma unroll
        for (int e = 0; e < 8; ++e) {
            if (ei == e) { loc = rc[e]; rc[e] = rc[e] + 1; }
        }
        const bool keepit = loc < CAP;
        gate_final[s] = keepit ? gate_top[s] : 0.f;
        if (keepit) {
            token_list[ei * CAP + loc] = s;
        } else {
            const int d = atomicAdd(&dropctr, 1);
            sdrop[d] = s;
        }
    }
    __syncthreads();

    const int nd = dropctr;
    for (int d = 0; d < nd; ++d) {
        const int s = sdrop[d];
        *(float2*)(out + (size_t)s * M_DIM + t * 2) = make_float2(0.f, 0.f);
    }
}

// ---------------------------------------------------------------------------
// K3: MFMA grouped GEMM1 + bias + ReLU -> h (bf16).
// 128x64 tile (1024 blocks -> 4 blocks/CU), single-buffer swizzled LDS.
// ---------------------------------------------------------------------------
__global__ __launch_bounds__(256, 4) void ffn1_mfma(
    const unsigned short* __restrict__ xb, const unsigned short* __restrict__ w1t,
    const float* __restrict__ b1, const int* __restrict__ tok,
    const int* __restrict__ kept, unsigned short* __restrict__ h)
{
    const int b = blockIdx.x;          // 1024 = (8ct*16nt) | 8e
    const int e = b & 7;
    const int r = b >> 3;
    const int ct = r >> 4, nt = r & 15;
    const int c0 = ct * 128, n0 = nt * 64;
    if (c0 >= kept[e]) return;

    __shared__ __align__(16) short Alds[128 * 64];
    __shared__ __align__(16) short Blds[64 * 64];
    __shared__ int srow[128];

    const int t = threadIdx.x;
    const int wave = t >> 6, lane = t & 63;
    const int wm = wave & 1, wn = wave >> 1;
    const int q = lane >> 4, lr = lane & 15;

    if (t < 128) srow[t] = tok[e * CAP + c0 + t];
    __syncthreads();

    f32x4 acc[4][2];
#pragma unroll
    for (int mi = 0; mi < 4; ++mi)
#pragma unroll
        for (int ni = 0; ni < 2; ++ni) acc[mi][ni] = (f32x4){0.f, 0.f, 0.f, 0.f};

    for (int kb = 0; kb < M_DIM; kb += 64) {
        __syncthreads();
#pragma unroll
        for (int i = 0; i < 4; ++i) {
            const int lin = (i * 4 + wave) * 64 + lane;
            const int row = lin >> 3;
            const int ch = (lin & 7) ^ (row & 7);
            async_copy16(xb + (size_t)srow[row] * M_DIM + kb + ch * 8,
                         &Alds[lin * 8]);
        }
#pragma unroll
        for (int i = 0; i < 2; ++i) {
            const int lin = (i * 4 + wave) * 64 + lane;
            const int row = lin >> 3;
            const int ch = (lin & 7) ^ (row & 7);
            async_copy16(w1t + ((size_t)e * H_DIM + n0 + row) * M_DIM + kb + ch * 8,
                         &Blds[lin * 8]);
        }
        __syncthreads();

#pragma unroll
        for (int kk = 0; kk < 64; kk += 32) {
            const int cb = kk >> 3;
            bf16x8 af[4], bfv[2];
#pragma unroll
            for (int mi = 0; mi < 4; ++mi) {
                const int R = wm * 64 + mi * 16 + lr;
                af[mi] = *(const bf16x8*)(&Alds[(R * 8 + ((cb + q) ^ (R & 7))) * 8]);
            }
#pragma unroll
            for (int ni = 0; ni < 2; ++ni) {
                const int R = wn * 32 + ni * 16 + lr;
                bfv[ni] = *(const bf16x8*)(&Blds[(R * 8 + ((cb + q) ^ (R & 7))) * 8]);
            }
#pragma unroll
            for (int mi = 0; mi < 4; ++mi)
#pragma unroll
                for (int ni = 0; ni < 2; ++ni)
                    acc[mi][ni] = __builtin_amdgcn_mfma_f32_16x16x32_bf16(
                        af[mi], bfv[ni], acc[mi][ni], 0, 0, 0);
        }
    }

#pragma unroll
    for (int ni = 0; ni < 2; ++ni) {
        const int col = n0 + wn * 32 + ni * 16 + lr;
        const float bias = b1[e * H_DIM + col];
#pragma unroll
        for (int mi = 0; mi < 4; ++mi) {
            const int rowl = wm * 64 + mi * 16 + q * 4;
            const size_t basep = (size_t)(e * CAP + c0 + rowl) * H_DIM + col;
#pragma unroll
            for (int r2 = 0; r2 < 4; ++r2) {
                const float v = fmaxf(acc[mi][ni][r2] + bias, 0.f);
                h[basep + (size_t)r2 * H_DIM] = f2bf(v);
            }
        }
    }
}

// ---------------------------------------------------------------------------
// K4: MFMA grouped GEMM2, 64x64 tile (1024 blocks -> 4 blocks/CU),
// single-buffer swizzled LDS, gate-scaled scatter.
// ---------------------------------------------------------------------------
__global__ __launch_bounds__(256, 4) void ffn2_mfma(
    const unsigned short* __restrict__ h, const unsigned short* __restrict__ w2t,
    const float* __restrict__ b2, const int* __restrict__ tok,
    const int* __restrict__ kept, const float* __restrict__ gate_final,
    float* __restrict__ out)
{
    const int b = blockIdx.x;          // 1024 = (16ct*8nt) | 8e
    const int e = b & 7;
    const int r = b >> 3;
    const int ct = r >> 3, nt = r & 7;
    const int c0 = ct * 64, n0 = nt * 64;
    if (c0 >= kept[e]) return;

    __shared__ __align__(16) short Alds[64 * 64];
    __shared__ __align__(16) short Blds[64 * 64];
    __shared__ int   stok[64];
    __shared__ float sgf[64];

    const int t = threadIdx.x;
    const int wave = t >> 6, lane = t & 63;
    const int wm = wave & 1, wn = wave >> 1;
    const int q = lane >> 4, lr = lane & 15;

    if (t < 64) {
        const int tk = tok[e * CAP + c0 + t];
        stok[t] = tk;
        sgf[t] = (tk != S_TOK) ? gate_final[tk] : 0.f;
    }

    f32x4 acc[2][2];
#pragma unroll
    for (int mi = 0; mi < 2; ++mi)
#pragma unroll
        for (int ni = 0; ni < 2; ++ni) acc[mi][ni] = (f32x4){0.f, 0.f, 0.f, 0.f};

    for (int kb = 0; kb < H_DIM; kb += 64) {
        __syncthreads();
#pragma unroll
        for (int i = 0; i < 2; ++i) {
            const int lin = (i * 4 + wave) * 64 + lane;
            const int row = lin >> 3;
            const int ch = (lin & 7) ^ (row & 7);
            async_copy16(h + (size_t)(e * CAP + c0 + row) * H_DIM + kb + ch * 8,
                         &Alds[lin * 8]);
        }
#pragma unroll
        for (int i = 0; i < 2; ++i) {
            const int lin = (i * 4 + wave) * 64 + lane;
            const int row = lin >> 3;
            const int ch = (lin & 7) ^ (row & 7);
            async_copy16(w2t + ((size_t)e * M_DIM + n0 + row) * H_DIM + kb + ch * 8,
                         &Blds[lin * 8]);
        }
        __syncthreads();

#pragma unroll
        for (int kk = 0; kk < 64; kk += 32) {
            const int cb = kk >> 3;
            bf16x8 af[2], bfv[2];
#pragma unroll
            for (int mi = 0; mi < 2; ++mi) {
                const int R = wm * 32 + mi * 16 + lr;
                af[mi] = *(const bf16x8*)(&Alds[(R * 8 + ((cb + q) ^ (R & 7))) * 8]);
            }
#pragma unroll
            for (int ni = 0; ni < 2; ++ni) {
                const int R = wn * 32 + ni * 16 + lr;
                bfv[ni] = *(const bf16x8*)(&Blds[(R * 8 + ((cb + q) ^ (R & 7))) * 8]);
            }
#pragma unroll
            for (int mi = 0; mi < 2; ++mi)
#pragma unroll
                for (int ni = 0; ni < 2; ++ni)
                    acc[mi][ni] = __builtin_amdgcn_mfma_f32_16x16x32_bf16(
                        af[mi], bfv[ni], acc[mi][ni], 0, 0, 0);
        }
    }

#pragma unroll
    for (int ni = 0; ni < 2; ++ni) {
        const int col = n0 + wn * 32 + ni * 16 + lr;
        const float bias = b2[e * M_DIM + col];
#pragma unroll
        for (int mi = 0; mi < 2; ++mi) {
            const int rowl = wm * 32 + mi * 16 + q * 4;
#pragma unroll
            for (int r2 = 0; r2 < 4; ++r2) {
                const int slot = rowl + r2;
                const int tokid = stok[slot];
                if (tokid != S_TOK) {
                    out[(size_t)tokid * M_DIM + col] = sgf[slot] * (acc[mi][ni][r2] + bias);
                }
            }
        }
    }
}

// ---------------------------------------------------------------------------
extern "C" void kernel_launch(void* const* d_in, const int* in_sizes, int n_in,
                              void* d_out, int out_size, void* d_ws, size_t ws_size,
                              hipStream_t stream) {
    const float* feats = (const float*)d_in[0];
    const float* wg    = (const float*)d_in[1];
    const float* w1    = (const float*)d_in[2];
    const float* b1    = (const float*)d_in[3];
    const float* w2    = (const float*)d_in[4];
    const float* b2    = (const float*)d_in[5];
    float* out = (float*)d_out;

    char* ws = (char*)d_ws;
    size_t off = 0;
    unsigned short* h   = (unsigned short*)(ws + off); off += (size_t)E_NUM * CAP * H_DIM * 2;
    unsigned short* xb  = (unsigned short*)(ws + off); off += (size_t)(S_TOK + 1) * M_DIM * 2;
    unsigned short* w1t = (unsigned short*)(ws + off); off += (size_t)E_NUM * H_DIM * M_DIM * 2;
    unsigned short* w2t = (unsigned short*)(ws + off); off += (size_t)E_NUM * M_DIM * H_DIM * 2;
    int*   idx        = (int*)(ws + off);   off += (size_t)S_TOK * 4;
    float* gate_top   = (float*)(ws + off); off += (size_t)S_TOK * 4;
    float* gate_final = (float*)(ws + off); off += (size_t)S_TOK * 4;
    float* gates_psum = (float*)(ws + off); off += (size_t)NGATE_BLK * 8 * 4;
    int*   token_list = (int*)(ws + off);   off += (size_t)S_TOK * 4;
    int*   kept       = (int*)(ws + off);   off += 64;
    (void)ws_size; (void)n_in; (void)in_sizes;

    prep_kernel<<<NGATE_BLK + 8192, 256, 0, stream>>>(
        feats, wg, idx, gate_top, gates_psum, xb, w1, w1t, w2, w2t);
    scan_kernel<<<1, 256, 0, stream>>>(idx, gate_top, gates_psum, gate_final,
                                       token_list, kept, out);
    ffn1_mfma<<<1024, 256, 0, stream>>>(xb, w1t, b1, token_list, kept, h);
    ffn2_mfma<<<1024, 256, 0, stream>>>(h, w2t, b2, token_list, kept,
                                        gate_final, out);
}